// Round 8
// baseline (379.888 us; speedup 1.0000x reference)
//
#include <hip/hip_runtime.h>

#define C_IN 256
#define C_OUT 256
#define NH 4
#define HD 64
#define NEG_SLOPE 0.2f

typedef _Float16 half8 __attribute__((ext_vector_type(8)));
typedef _Float16 half4v __attribute__((ext_vector_type(4)));
typedef float floatx4 __attribute__((ext_vector_type(4)));

// ---------------------------------------------------------------------------
// K1: collapse (Wl,att_l)->Ws[:,0:4], (Wr,att_r)->Ws[:,4:8]; biases -> bs[8].
// ---------------------------------------------------------------------------
__global__ void make_eff_w(const float* __restrict__ Wl, const float* __restrict__ Wr,
                           const float* __restrict__ bl, const float* __restrict__ br,
                           const float* __restrict__ attl, const float* __restrict__ attr,
                           float* __restrict__ Ws, float* __restrict__ bs)
{
    int c = blockIdx.x;
    int t = threadIdx.x;          // t = h*64 + d
    int h = t >> 6, d = t & 63;
    float al = attl[t], ar = attr[t];
    float vl, vr;
    if (c < C_IN) { vl = Wl[c * C_OUT + t] * al; vr = Wr[c * C_OUT + t] * ar; }
    else          { vl = bl[t] * al;             vr = br[t] * ar; }
#pragma unroll
    for (int off = 32; off >= 1; off >>= 1) {
        vl += __shfl_xor(vl, off, 64);
        vr += __shfl_xor(vr, off, 64);
    }
    if (d == 0) {
        if (c < C_IN) { Ws[c * 8 + h] = vl; Ws[c * 8 + 4 + h] = vr; }
        else          { bs[h] = vl;         bs[4 + h] = vr; }
    }
}

// ---------------------------------------------------------------------------
// Transpose Wv (k-major fp32) -> WvT (n-major f16).
// ---------------------------------------------------------------------------
__global__ void transpose_w(const float* __restrict__ Wv, _Float16* __restrict__ WvT)
{
    int idx = blockIdx.x * 256 + threadIdx.x;
    int n = idx >> 8, k = idx & 255;
    WvT[n * 256 + k] = (_Float16)Wv[k * 256 + n];
}

// ---------------------------------------------------------------------------
// GEMM v8: wave-synchronous, barrier-free (no __syncthreads). One wave owns a
// 16x256 output strip. Per K-step (32):
//  - COALESCED x load: lane (srow=lane>>3, schunk=lane&7) reads float4 at
//    x[(m0+srow)+..][k0+schunk*4] -> 8 lanes x 16B = 128B per row. Two rounds
//    (rows srow, srow+8). Next step's loads issued BEFORE consuming LDS.
//  - Per-wave LDS transpose: f32->f16, ds_write As[wid][row][chunk], then
//    wave_barrier() (compile-time fence, 0 instrs; DS ops are in-order per
//    wave) and ds_read the MFMA A-frag As[wid][r16][quad*8] (v6's exact
//    proven fragment layout; pad 40 halfs = 80B stride, 16B-aligned, 2-way
//    banks = free).
//  - B-frag direct from cache (proven OK in v7; WvT 131KB is L2-resident).
//  - s-fusion on the f32 values (lane covers rows srow/srow+8, k schunk*4+j);
//    reduced over the 8 schunk-lanes via shfl_xor 1,2,4.
// Waves fully independent -> deep K-step pipelining, no barrier drain.
// ---------------------------------------------------------------------------
__global__ __launch_bounds__(256) void gemm_xv(const float* __restrict__ x,
    const _Float16* __restrict__ WvT, const float* __restrict__ bv,
    const float* __restrict__ Ws, const float* __restrict__ bs,
    _Float16* __restrict__ xv, float* __restrict__ s, int M)
{
    __shared__ __align__(16) _Float16 As[4][16][40];
    int wid = threadIdx.x >> 6, lane = threadIdx.x & 63;
    int wv = blockIdx.x * 4 + wid;
    int m0 = wv * 16;
    if (m0 >= M) return;                     // safe: no block-wide barriers

    int r16 = lane & 15, quad = lane >> 4;
    int srow = lane >> 3, schunk = lane & 7;

    int g0 = m0 + srow, g1 = m0 + srow + 8;
    int g0c = g0 < M ? g0 : M - 1;           // load-clamp; stores guarded
    int g1c = g1 < M ? g1 : M - 1;
    const float4* xr0 = (const float4*)(x + (size_t)g0c * 256);
    const float4* xr1 = (const float4*)(x + (size_t)g1c * 256);

    floatx4 acc[16];
#pragma unroll
    for (int cg = 0; cg < 16; ++cg) acc[cg] = (floatx4){0.f, 0.f, 0.f, 0.f};
    float sacc0[8], sacc1[8];
#pragma unroll
    for (int j = 0; j < 8; ++j) { sacc0[j] = 0.f; sacc1[j] = 0.f; }

    float4 va = xr0[schunk];                 // prefetch k-step 0
    float4 vb = xr1[schunk];

    for (int ks = 0; ks < 8; ++ks) {
        int k0 = ks * 32;
        float4 ca = va, cb = vb;
        if (ks < 7) {                        // issue next step's loads early
            va = xr0[(ks + 1) * 8 + schunk];
            vb = xr1[(ks + 1) * 8 + schunk];
        }

        half4v ha, hb;
        ha[0] = (_Float16)ca.x; ha[1] = (_Float16)ca.y;
        ha[2] = (_Float16)ca.z; ha[3] = (_Float16)ca.w;
        hb[0] = (_Float16)cb.x; hb[1] = (_Float16)cb.y;
        hb[2] = (_Float16)cb.z; hb[3] = (_Float16)cb.w;
        *(half4v*)&As[wid][srow][schunk * 4]     = ha;
        *(half4v*)&As[wid][srow + 8][schunk * 4] = hb;
        __builtin_amdgcn_wave_barrier();
        half8 af = *(const half8*)&As[wid][r16][quad * 8];
        __builtin_amdgcn_wave_barrier();

        // fused node-scores partials (f32, rows g0/g1, k = k0+schunk*4+j2)
        const float* wsr = Ws + (unsigned)(k0 + schunk * 4) * 8;
        float fa[4] = {ca.x, ca.y, ca.z, ca.w};
        float fb[4] = {cb.x, cb.y, cb.z, cb.w};
#pragma unroll
        for (int j2 = 0; j2 < 4; ++j2) {
            float4 wa = *(const float4*)(wsr + j2 * 8);
            float4 wb = *(const float4*)(wsr + j2 * 8 + 4);
            sacc0[0] += fa[j2] * wa.x; sacc0[1] += fa[j2] * wa.y;
            sacc0[2] += fa[j2] * wa.z; sacc0[3] += fa[j2] * wa.w;
            sacc0[4] += fa[j2] * wb.x; sacc0[5] += fa[j2] * wb.y;
            sacc0[6] += fa[j2] * wb.z; sacc0[7] += fa[j2] * wb.w;
            sacc1[0] += fb[j2] * wa.x; sacc1[1] += fb[j2] * wa.y;
            sacc1[2] += fb[j2] * wa.z; sacc1[3] += fb[j2] * wa.w;
            sacc1[4] += fb[j2] * wb.x; sacc1[5] += fb[j2] * wb.y;
            sacc1[6] += fb[j2] * wb.z; sacc1[7] += fb[j2] * wb.w;
        }

#pragma unroll
        for (int cg = 0; cg < 16; ++cg) {
            half8 bf = *(const half8*)(WvT + (unsigned)((cg * 16 + r16) * 256 + k0 + quad * 8));
            acc[cg] = __builtin_amdgcn_mfma_f32_16x16x32_f16(af, bf, acc[cg], 0, 0, 0);
        }
    }

    // ---- xv epilogue: C layout col=lane&15, row=quad*4+rr (v7-verified). ----
#pragma unroll
    for (int cg = 0; cg < 16; ++cg) {
        int gcol = cg * 16 + r16;
        float bias = bv[gcol];
#pragma unroll
        for (int rr = 0; rr < 4; ++rr) {
            int grow = m0 + quad * 4 + rr;
            if (grow < M)
                xv[(size_t)grow * 256 + gcol] = (_Float16)(acc[cg][rr] + bias);
        }
    }

    // ---- s epilogue: reduce over the 8 schunk-lanes of each row group. ----
#pragma unroll
    for (int o = 1; o <= 4; o <<= 1)
#pragma unroll
        for (int j = 0; j < 8; ++j) {
            sacc0[j] += __shfl_xor(sacc0[j], o, 64);
            sacc1[j] += __shfl_xor(sacc1[j], o, 64);
        }
    if (schunk == 0) {
        if (g0 < M) {
            *(float4*)(s + (size_t)g0 * 8)     = make_float4(sacc0[0] + bs[0], sacc0[1] + bs[1], sacc0[2] + bs[2], sacc0[3] + bs[3]);
            *(float4*)(s + (size_t)g0 * 8 + 4) = make_float4(sacc0[4] + bs[4], sacc0[5] + bs[5], sacc0[6] + bs[6], sacc0[7] + bs[7]);
        }
        if (g1 < M) {
            *(float4*)(s + (size_t)g1 * 8)     = make_float4(sacc1[0] + bs[0], sacc1[1] + bs[1], sacc1[2] + bs[2], sacc1[3] + bs[3]);
            *(float4*)(s + (size_t)g1 * 8 + 4) = make_float4(sacc1[4] + bs[4], sacc1[5] + bs[5], sacc1[6] + bs[6], sacc1[7] + bs[7]);
        }
    }
}

// ---------------------------------------------------------------------------
// CSR build (v6: 4 edges/thread via int4 loads).
// ---------------------------------------------------------------------------
__global__ void deg_kernel(const int* __restrict__ dst, int* __restrict__ deg, int E)
{
    int i = blockIdx.x * 256 + threadIdx.x;
    int base = i * 4;
    if (base >= E) return;
    if (base + 4 <= E) {
        int4 d = *(const int4*)(dst + base);
        atomicAdd(&deg[d.x], 1);
        atomicAdd(&deg[d.y], 1);
        atomicAdd(&deg[d.z], 1);
        atomicAdd(&deg[d.w], 1);
    } else {
        for (int k = base; k < E; ++k) atomicAdd(&deg[dst[k]], 1);
    }
}

__global__ void scan_part(const int* __restrict__ deg, int* __restrict__ partials,
                          int N, int chunk)
{
    __shared__ int sd[256];
    int b = blockIdx.x, t = threadIdx.x;
    int idx = b * chunk + t;
    int v = (t < chunk && idx < N) ? deg[idx] : 0;
    sd[t] = v; __syncthreads();
    for (int off = 128; off >= 1; off >>= 1) {
        if (t < off) sd[t] += sd[t + off];
        __syncthreads();
    }
    if (t == 0) partials[b] = sd[0];
}

__global__ void scan_partials(const int* __restrict__ partials, int* __restrict__ pscan)
{
    __shared__ int sd[256];
    int t = threadIdx.x;
    int v = partials[t];
    sd[t] = v; __syncthreads();
    for (int off = 1; off < 256; off <<= 1) {
        int x = (t >= off) ? sd[t - off] : 0;
        __syncthreads();
        sd[t] += x;
        __syncthreads();
    }
    pscan[t] = sd[t] - v;  // exclusive
}

__global__ void scan_final(const int* __restrict__ deg, const int* __restrict__ pscan,
                           int* __restrict__ offs, int N, int chunk)
{
    __shared__ int sd[256];
    int b = blockIdx.x, t = threadIdx.x;
    int idx = b * chunk + t;
    int v = (t < chunk && idx < N) ? deg[idx] : 0;
    sd[t] = v; __syncthreads();
    for (int off = 1; off < 256; off <<= 1) {
        int x = (t >= off) ? sd[t - off] : 0;
        __syncthreads();
        sd[t] += x;
        __syncthreads();
    }
    int incl = sd[t], excl = incl - v;
    int base = pscan[b];
    if (t < chunk && idx < N) offs[idx] = base + excl;
    if (idx == N - 1) offs[N] = base + incl;  // == E
}

__global__ void scatter_kernel(const int* __restrict__ src, const int* __restrict__ dst,
                               const int* __restrict__ offs, int* __restrict__ cursor,
                               int* __restrict__ csr_src, int E)
{
    int i = blockIdx.x * 256 + threadIdx.x;
    int base = i * 4;
    if (base >= E) return;
    if (base + 4 <= E) {
        int4 d  = *(const int4*)(dst + base);
        int4 sv = *(const int4*)(src + base);
        int p0 = offs[d.x] + atomicAdd(&cursor[d.x], 1); csr_src[p0] = sv.x;
        int p1 = offs[d.y] + atomicAdd(&cursor[d.y], 1); csr_src[p1] = sv.y;
        int p2 = offs[d.z] + atomicAdd(&cursor[d.z], 1); csr_src[p2] = sv.z;
        int p3 = offs[d.w] + atomicAdd(&cursor[d.w], 1); csr_src[p3] = sv.w;
    } else {
        for (int k = base; k < E; ++k) {
            int d = dst[k];
            int p = offs[d] + atomicAdd(&cursor[d], 1);
            csr_src[p] = src[k];
        }
    }
}

// ---------------------------------------------------------------------------
// agg = (hlr + segsum(hlr[src] by dst)) / (1+deg). EIGHT threads per node.
// ---------------------------------------------------------------------------
__global__ void agg_kernel(const float* __restrict__ s, const int* __restrict__ csr_src,
                           const int* __restrict__ offs, const int* __restrict__ deg,
                           float* __restrict__ aggl, float* __restrict__ aggr, int N)
{
    int gid = blockIdx.x * 256 + threadIdx.x;
    int n = gid >> 3, c = gid & 7;
    if (n >= N) return;
    int off = offs[n], dg = deg[n];
    float acc = s[(size_t)n * 8 + c];
    int i = 0;
    for (; i + 4 <= dg; i += 4) {
        int p0 = csr_src[off + i];
        int p1 = csr_src[off + i + 1];
        int p2 = csr_src[off + i + 2];
        int p3 = csr_src[off + i + 3];
        float v0 = s[(size_t)p0 * 8 + c];
        float v1 = s[(size_t)p1 * 8 + c];
        float v2 = s[(size_t)p2 * 8 + c];
        float v3 = s[(size_t)p3 * 8 + c];
        acc += (v0 + v1) + (v2 + v3);
    }
    for (; i < dg; ++i) acc += s[(size_t)csr_src[off + i] * 8 + c];
    acc *= 1.0f / (1.0f + (float)dg);
    if (c < 4) aggl[(size_t)n * 4 + c]     = acc;
    else       aggr[(size_t)n * 4 + c - 4] = acc;
}

// ---------------------------------------------------------------------------
// Fused softmax + value aggregation — v5 (unchanged).
// ---------------------------------------------------------------------------
template<int SZ>
__device__ __forceinline__ void gather_sub(int cs, float w, int base, int grp, int lof,
    const _Float16* __restrict__ xv,
    float& o0, float& o1, float& o2, float& o3)
{
    half4v hv[SZ];
#pragma unroll
    for (int j = 0; j < SZ; ++j) {
        int sidx = __builtin_amdgcn_readlane(cs, base + j);   // SGPR row index
        hv[j] = *(const half4v*)(xv + (((unsigned)sidx << 8) + lof));
    }
#pragma unroll
    for (int j = 0; j < SZ; ++j) {
        float wv = __shfl(w, grp + base + j, 64);
        o0 += wv * (float)hv[j][0];
        o1 += wv * (float)hv[j][1];
        o2 += wv * (float)hv[j][2];
        o3 += wv * (float)hv[j][3];
    }
}

__device__ __forceinline__ void do_chunk(int cs, float w, int cnt, int grp, int lof,
    const _Float16* __restrict__ xv,
    float& o0, float& o1, float& o2, float& o3)
{
    if (cnt == 16) { gather_sub<16>(cs, w, 0, grp, lof, xv, o0, o1, o2, o3); return; }
    int b = 0;
    if (cnt & 8) { gather_sub<8>(cs, w, b, grp, lof, xv, o0, o1, o2, o3); b += 8; }
    if (cnt & 4) { gather_sub<4>(cs, w, b, grp, lof, xv, o0, o1, o2, o3); b += 4; }
    if (cnt & 2) { gather_sub<2>(cs, w, b, grp, lof, xv, o0, o1, o2, o3); b += 2; }
    if (cnt & 1) { gather_sub<1>(cs, w, b, grp, lof, xv, o0, o1, o2, o3); }
}

__global__ __launch_bounds__(256) void attn_out(const float* __restrict__ aggl,
    const float* __restrict__ aggr, const int* __restrict__ csr_src,
    const int* __restrict__ offs, const int* __restrict__ deg,
    const _Float16* __restrict__ xv, float* __restrict__ out, int N)
{
    int wid = threadIdx.x >> 6, lane = threadIdx.x & 63;
    int n = blockIdx.x * 4 + wid;
    if (n >= N) return;
    int myhead = lane >> 4, myedge = lane & 15, grp = lane & 48;
    int lof = lane << 2;
    int off = offs[n], dg = deg[n];
    const int* cb = csr_src + off;
    float ar = aggr[(unsigned)(n * 4 + myhead)];

    float o0 = 0.f, o1 = 0.f, o2 = 0.f, o3 = 0.f;

    // ---- Phase A: all weight-phase loads issued upfront (independent). ----
    int cs0 = 0, cs1 = 0, cs2 = 0, cs3 = 0;
    int e1 = myedge + 16, e2 = myedge + 32, e3 = myedge + 48;
    if (myedge < dg) cs0 = cb[myedge];
    if (e1 < dg)     cs1 = cb[e1];
    if (e2 < dg)     cs2 = cb[e2];
    if (e3 < dg)     cs3 = cb[e3];
    float a0 = 0.f, a1 = 0.f, a2 = 0.f, a3 = 0.f;
    if (myedge < dg) a0 = aggl[(unsigned)((cs0 << 2) + myhead)];
    if (e1 < dg)     a1 = aggl[(unsigned)((cs1 << 2) + myhead)];
    if (e2 < dg)     a2 = aggl[(unsigned)((cs2 << 2) + myhead)];
    if (e3 < dg)     a3 = aggl[(unsigned)((cs3 << 2) + myhead)];
    float w0 = 0.f, w1 = 0.f, w2 = 0.f, w3 = 0.f;
    if (myedge < dg) { float e = a0 + ar; e = (e > 0.f) ? e : NEG_SLOPE * e; w0 = __expf(e); }
    if (e1 < dg)     { float e = a1 + ar; e = (e > 0.f) ? e : NEG_SLOPE * e; w1 = __expf(e); }
    if (e2 < dg)     { float e = a2 + ar; e = (e > 0.f) ? e : NEG_SLOPE * e; w2 = __expf(e); }
    if (e3 < dg)     { float e = a3 + ar; e = (e > 0.f) ? e : NEG_SLOPE * e; w3 = __expf(e); }
    float denom = w0; denom += w1; denom += w2; denom += w3;

    // ---- Phase B: gather rounds, weights already in registers. ----
    int c0 = dg < 16 ? dg : 16;
    do_chunk(cs0, w0, c0, grp, lof, xv, o0, o1, o2, o3);
    if (dg > 16) {
        int c1 = dg - 16 < 16 ? dg - 16 : 16;
        do_chunk(cs1, w1, c1, grp, lof, xv, o0, o1, o2, o3);
    }
    if (dg > 32) {
        int c2 = dg - 32 < 16 ? dg - 32 : 16;
        do_chunk(cs2, w2, c2, grp, lof, xv, o0, o1, o2, o3);
    }
    if (dg > 48) {
        int c3 = dg - 48 < 16 ? dg - 48 : 16;
        do_chunk(cs3, w3, c3, grp, lof, xv, o0, o1, o2, o3);
    }
    // Fallback for dg > 64 (essentially never for Poisson(16); correctness).
    for (int b = 64; b < dg; b += 16) {
        int cs = 0; float w = 0.f;
        if (b + myedge < dg) {
            cs = cb[b + myedge];
            float e = aggl[(unsigned)((cs << 2) + myhead)] + ar;
            e = (e > 0.f) ? e : NEG_SLOPE * e;
            w = __expf(e);
        }
        denom += w;
        int cnt = dg - b < 16 ? dg - b : 16;
        do_chunk(cs, w, cnt, grp, lof, xv, o0, o1, o2, o3);
    }

    // Sum denom over the 16 lanes of this head group.
#pragma unroll
    for (int o = 1; o <= 8; o <<= 1) denom += __shfl_xor(denom, o, 64);
    float inv = 1.0f / fmaxf(denom, 1e-16f);
    floatx4 res = {o0 * inv, o1 * inv, o2 * inv, o3 * inv};
    __builtin_nontemporal_store(res, (floatx4*)(out + (size_t)n * 256 + lof));
}

// ---------------------------------------------------------------------------
extern "C" void kernel_launch(void* const* d_in, const int* in_sizes, int n_in,
                              void* d_out, int out_size, void* d_ws, size_t ws_size,
                              hipStream_t stream)
{
    const float* x    = (const float*)d_in[0];
    const int*   src  = (const int*)d_in[1];
    const int*   dst  = (const int*)d_in[2];
    const float* Wl   = (const float*)d_in[3];
    const float* bl   = (const float*)d_in[4];
    const float* Wr   = (const float*)d_in[5];
    const float* br   = (const float*)d_in[6];
    const float* Wv   = (const float*)d_in[7];
    const float* bv   = (const float*)d_in[8];
    const float* attl = (const float*)d_in[9];
    const float* attr = (const float*)d_in[10];
    float* out = (float*)d_out;

    int N = in_sizes[0] / C_IN;
    int E = in_sizes[1];

    char* p = (char*)d_ws;
    auto alloc = [&](size_t bytes) -> void* {
        uintptr_t q = (uintptr_t)p;
        q = (q + 255) & ~(uintptr_t)255;
        p = (char*)(q + bytes);
        return (void*)q;
    };
    float* Ws     = (float*)alloc((size_t)C_IN * 8 * sizeof(float));
    float* bs     = (float*)alloc(8 * sizeof(float));
    float* s      = (float*)alloc((size_t)N * 8 * sizeof(float));
    float* aggl   = (float*)alloc((size_t)N * 4 * sizeof(float));
    float* aggr   = (float*)alloc((size_t)N * 4 * sizeof(float));
    int* deg      = (int*)alloc((size_t)N * sizeof(int));
    int* offs     = (int*)alloc((size_t)(N + 1) * sizeof(int));
    int* cursor   = (int*)alloc((size_t)N * sizeof(int));
    int* partials = (int*)alloc(256 * sizeof(int));
    int* pscan    = (int*)alloc(256 * sizeof(int));
    int* csr_src  = (int*)alloc((size_t)E * sizeof(int));
    _Float16* WvT = (_Float16*)alloc((size_t)C_IN * C_OUT * sizeof(_Float16));
    _Float16* xv  = (_Float16*)alloc((size_t)N * C_OUT * sizeof(_Float16));

    hipMemsetAsync(deg, 0, (size_t)N * sizeof(int), stream);
    hipMemsetAsync(cursor, 0, (size_t)N * sizeof(int), stream);

    make_eff_w<<<C_IN + 1, 256, 0, stream>>>(Wl, Wr, bl, br, attl, attr, Ws, bs);
    transpose_w<<<(C_IN * C_OUT) / 256, 256, 0, stream>>>(Wv, WvT);
    int nstrips = (N + 15) / 16;
    gemm_xv<<<(nstrips + 3) / 4, 256, 0, stream>>>(x, WvT, bv, Ws, bs, xv, s, N);
    deg_kernel<<<((E + 3) / 4 + 255) / 256, 256, 0, stream>>>(dst, deg, E);
    int chunk = (N + 255) / 256;
    scan_part<<<256, 256, 0, stream>>>(deg, partials, N, chunk);
    scan_partials<<<1, 256, 0, stream>>>(partials, pscan);
    scan_final<<<256, 256, 0, stream>>>(deg, pscan, offs, N, chunk);
    scatter_kernel<<<((E + 3) / 4 + 255) / 256, 256, 0, stream>>>(src, dst, offs, cursor, csr_src, E);
    agg_kernel<<<(N * 8 + 255) / 256, 256, 0, stream>>>(s, csr_src, offs, deg, aggl, aggr, N);
    attn_out<<<(N + 3) / 4, 256, 0, stream>>>(aggl, aggr, csr_src, offs, deg, xv, out, N);
}

// Round 9
// 342.294 us; speedup vs baseline: 1.1098x; 1.1098x over previous
//
#include <hip/hip_runtime.h>

#define C_IN 256
#define C_OUT 256
#define NH 4
#define HD 64
#define NEG_SLOPE 0.2f

typedef _Float16 half8 __attribute__((ext_vector_type(8)));
typedef _Float16 half4v __attribute__((ext_vector_type(4)));
typedef float floatx4 __attribute__((ext_vector_type(4)));

// ---------------------------------------------------------------------------
// K1: collapse (Wl,att_l)->Ws[:,0:4], (Wr,att_r)->Ws[:,4:8]; biases -> bs[8].
// ---------------------------------------------------------------------------
__global__ void make_eff_w(const float* __restrict__ Wl, const float* __restrict__ Wr,
                           const float* __restrict__ bl, const float* __restrict__ br,
                           const float* __restrict__ attl, const float* __restrict__ attr,
                           float* __restrict__ Ws, float* __restrict__ bs)
{
    int c = blockIdx.x;
    int t = threadIdx.x;          // t = h*64 + d
    int h = t >> 6, d = t & 63;
    float al = attl[t], ar = attr[t];
    float vl, vr;
    if (c < C_IN) { vl = Wl[c * C_OUT + t] * al; vr = Wr[c * C_OUT + t] * ar; }
    else          { vl = bl[t] * al;             vr = br[t] * ar; }
#pragma unroll
    for (int off = 32; off >= 1; off >>= 1) {
        vl += __shfl_xor(vl, off, 64);
        vr += __shfl_xor(vr, off, 64);
    }
    if (d == 0) {
        if (c < C_IN) { Ws[c * 8 + h] = vl; Ws[c * 8 + 4 + h] = vr; }
        else          { bs[h] = vl;         bs[4 + h] = vr; }
    }
}

// ---------------------------------------------------------------------------
// Transpose Wv (k-major fp32) -> WvT (n-major f16).
// ---------------------------------------------------------------------------
__global__ void transpose_w(const float* __restrict__ Wv, _Float16* __restrict__ WvT)
{
    int idx = blockIdx.x * 256 + threadIdx.x;
    int n = idx >> 8, k = idx & 255;
    WvT[n * 256 + k] = (_Float16)Wv[k * 256 + n];
}

// ---------------------------------------------------------------------------
// GEMM v9 = proven v6 structure (LDS-staged A and B, 2 barriers/K-step,
// fused node_scores on y==0) with ONE parameter change: N-tile 128 -> 64.
// Grid doubles to (391 x 4) = 1564 blocks (6.1/CU vs 3.05) lifting the
// occupancy cap 38% -> 76%; acc VGPRs halve (64 -> 32), LDS 20 -> 15.4 KB.
// All layouts / staging patterns / summation orders are v6-identical ->
// bit-identical outputs. (v7/v8 post-mortem: feeding B-frags from global
// = 16-way scattered loads, 2x slower than v6; LDS staging IS the win.)
// ---------------------------------------------------------------------------
__global__ __launch_bounds__(256) void gemm_xv(const float* __restrict__ x,
    const _Float16* __restrict__ WvT, const float* __restrict__ bv,
    const float* __restrict__ Ws, const float* __restrict__ bs,
    _Float16* __restrict__ xv, float* __restrict__ s, int M)
{
    __shared__ __align__(16) _Float16 As[128][40];
    __shared__ __align__(16) _Float16 Bs[64][40];
    int tid = threadIdx.x;
    int wid = tid >> 6, lane = tid & 63;
    int quad = lane >> 4, r16 = lane & 15;
    int m0 = blockIdx.x * 128, n0 = blockIdx.y * 64;
    bool do_s = (blockIdx.y == 0);

    floatx4 acc[2][4];
#pragma unroll
    for (int i = 0; i < 2; ++i)
#pragma unroll
        for (int j = 0; j < 4; ++j) acc[i][j] = (floatx4){0.f, 0.f, 0.f, 0.f};

    int arow = tid >> 3, af4 = tid & 7;
    int brow = tid >> 2, bg  = tid & 3;

    float sacc[4][8];
#pragma unroll
    for (int p = 0; p < 4; ++p)
#pragma unroll
        for (int j = 0; j < 8; ++j) sacc[p][j] = 0.f;

    for (int k0 = 0; k0 < 256; k0 += 32) {
        float w8[4][8];
        if (do_s) {
#pragma unroll
            for (int q = 0; q < 4; ++q) {
                const float4* wr = (const float4*)(Ws + (size_t)(k0 + af4 * 4 + q) * 8);
                float4 wa = wr[0], wb = wr[1];
                w8[q][0] = wa.x; w8[q][1] = wa.y; w8[q][2] = wa.z; w8[q][3] = wa.w;
                w8[q][4] = wb.x; w8[q][5] = wb.y; w8[q][6] = wb.z; w8[q][7] = wb.w;
            }
        }
#pragma unroll
        for (int p = 0; p < 4; ++p) {
            int rr = arow + p * 32;
            int gm = m0 + rr;
            float4 v = make_float4(0.f, 0.f, 0.f, 0.f);
            if (gm < M) v = *(const float4*)(x + (size_t)gm * 256 + k0 + af4 * 4);
            half4v tmp;
            tmp[0] = (_Float16)v.x; tmp[1] = (_Float16)v.y;
            tmp[2] = (_Float16)v.z; tmp[3] = (_Float16)v.w;
            *(half4v*)&As[rr][af4 * 4] = tmp;
            if (do_s) {
                float xq[4] = {v.x, v.y, v.z, v.w};
#pragma unroll
                for (int q = 0; q < 4; ++q)
#pragma unroll
                    for (int j = 0; j < 8; ++j)
                        sacc[p][j] += xq[q] * w8[q][j];
            }
        }
        // Bs: 64 rows, one round (brow = tid>>2 covers 0..63).
        *(float4*)&Bs[brow][bg * 8] = *(const float4*)(WvT + (size_t)(n0 + brow) * 256 + k0 + bg * 8);
        __syncthreads();
        half8 a[2], b[4];
#pragma unroll
        for (int rg = 0; rg < 2; ++rg)
            a[rg] = *(const half8*)&As[wid * 32 + rg * 16 + r16][quad * 8];
#pragma unroll
        for (int cg = 0; cg < 4; ++cg)
            b[cg] = *(const half8*)&Bs[cg * 16 + r16][quad * 8];
#pragma unroll
        for (int rg = 0; rg < 2; ++rg)
#pragma unroll
            for (int cg = 0; cg < 4; ++cg)
                acc[rg][cg] = __builtin_amdgcn_mfma_f32_16x16x32_f16(a[rg], b[cg], acc[rg][cg], 0, 0, 0);
        __syncthreads();
    }

    // ---- s epilogue (y==0 blocks): reduce sacc over the 8 af4-lanes. ----
    if (do_s) {
        float b0[8];
#pragma unroll
        for (int j = 0; j < 8; ++j) b0[j] = bs[j];
#pragma unroll
        for (int p = 0; p < 4; ++p) {
#pragma unroll
            for (int o = 1; o <= 4; o <<= 1)
#pragma unroll
                for (int j = 0; j < 8; ++j)
                    sacc[p][j] += __shfl_xor(sacc[p][j], o, 64);
            int gm = m0 + arow + p * 32;
            if (af4 == 0 && gm < M) {
                *(float4*)(s + (size_t)gm * 8)     = make_float4(sacc[p][0] + b0[0], sacc[p][1] + b0[1], sacc[p][2] + b0[2], sacc[p][3] + b0[3]);
                *(float4*)(s + (size_t)gm * 8 + 4) = make_float4(sacc[p][4] + b0[4], sacc[p][5] + b0[5], sacc[p][6] + b0[6], sacc[p][7] + b0[7]);
            }
        }
    }

#pragma unroll
    for (int rg = 0; rg < 2; ++rg) {
        int rbase = m0 + wid * 32 + rg * 16 + quad * 4;
#pragma unroll
        for (int cg = 0; cg < 4; ++cg) {
            int gcol = n0 + cg * 16 + r16;
            float bias = bv[gcol];
#pragma unroll
            for (int rr = 0; rr < 4; ++rr) {
                int grow = rbase + rr;
                if (grow < M)
                    xv[(size_t)grow * 256 + gcol] = (_Float16)(acc[rg][cg][rr] + bias);
            }
        }
    }
}

// ---------------------------------------------------------------------------
// CSR build (v6: 4 edges/thread via int4 loads).
// ---------------------------------------------------------------------------
__global__ void deg_kernel(const int* __restrict__ dst, int* __restrict__ deg, int E)
{
    int i = blockIdx.x * 256 + threadIdx.x;
    int base = i * 4;
    if (base >= E) return;
    if (base + 4 <= E) {
        int4 d = *(const int4*)(dst + base);
        atomicAdd(&deg[d.x], 1);
        atomicAdd(&deg[d.y], 1);
        atomicAdd(&deg[d.z], 1);
        atomicAdd(&deg[d.w], 1);
    } else {
        for (int k = base; k < E; ++k) atomicAdd(&deg[dst[k]], 1);
    }
}

__global__ void scan_part(const int* __restrict__ deg, int* __restrict__ partials,
                          int N, int chunk)
{
    __shared__ int sd[256];
    int b = blockIdx.x, t = threadIdx.x;
    int idx = b * chunk + t;
    int v = (t < chunk && idx < N) ? deg[idx] : 0;
    sd[t] = v; __syncthreads();
    for (int off = 128; off >= 1; off >>= 1) {
        if (t < off) sd[t] += sd[t + off];
        __syncthreads();
    }
    if (t == 0) partials[b] = sd[0];
}

__global__ void scan_partials(const int* __restrict__ partials, int* __restrict__ pscan)
{
    __shared__ int sd[256];
    int t = threadIdx.x;
    int v = partials[t];
    sd[t] = v; __syncthreads();
    for (int off = 1; off < 256; off <<= 1) {
        int x = (t >= off) ? sd[t - off] : 0;
        __syncthreads();
        sd[t] += x;
        __syncthreads();
    }
    pscan[t] = sd[t] - v;  // exclusive
}

__global__ void scan_final(const int* __restrict__ deg, const int* __restrict__ pscan,
                           int* __restrict__ offs, int N, int chunk)
{
    __shared__ int sd[256];
    int b = blockIdx.x, t = threadIdx.x;
    int idx = b * chunk + t;
    int v = (t < chunk && idx < N) ? deg[idx] : 0;
    sd[t] = v; __syncthreads();
    for (int off = 1; off < 256; off <<= 1) {
        int x = (t >= off) ? sd[t - off] : 0;
        __syncthreads();
        sd[t] += x;
        __syncthreads();
    }
    int incl = sd[t], excl = incl - v;
    int base = pscan[b];
    if (t < chunk && idx < N) offs[idx] = base + excl;
    if (idx == N - 1) offs[N] = base + incl;  // == E
}

__global__ void scatter_kernel(const int* __restrict__ src, const int* __restrict__ dst,
                               const int* __restrict__ offs, int* __restrict__ cursor,
                               int* __restrict__ csr_src, int E)
{
    int i = blockIdx.x * 256 + threadIdx.x;
    int base = i * 4;
    if (base >= E) return;
    if (base + 4 <= E) {
        int4 d  = *(const int4*)(dst + base);
        int4 sv = *(const int4*)(src + base);
        int p0 = offs[d.x] + atomicAdd(&cursor[d.x], 1); csr_src[p0] = sv.x;
        int p1 = offs[d.y] + atomicAdd(&cursor[d.y], 1); csr_src[p1] = sv.y;
        int p2 = offs[d.z] + atomicAdd(&cursor[d.z], 1); csr_src[p2] = sv.z;
        int p3 = offs[d.w] + atomicAdd(&cursor[d.w], 1); csr_src[p3] = sv.w;
    } else {
        for (int k = base; k < E; ++k) {
            int d = dst[k];
            int p = offs[d] + atomicAdd(&cursor[d], 1);
            csr_src[p] = src[k];
        }
    }
}

// ---------------------------------------------------------------------------
// agg = (hlr + segsum(hlr[src] by dst)) / (1+deg). EIGHT threads per node.
// ---------------------------------------------------------------------------
__global__ void agg_kernel(const float* __restrict__ s, const int* __restrict__ csr_src,
                           const int* __restrict__ offs, const int* __restrict__ deg,
                           float* __restrict__ aggl, float* __restrict__ aggr, int N)
{
    int gid = blockIdx.x * 256 + threadIdx.x;
    int n = gid >> 3, c = gid & 7;
    if (n >= N) return;
    int off = offs[n], dg = deg[n];
    float acc = s[(size_t)n * 8 + c];
    int i = 0;
    for (; i + 4 <= dg; i += 4) {
        int p0 = csr_src[off + i];
        int p1 = csr_src[off + i + 1];
        int p2 = csr_src[off + i + 2];
        int p3 = csr_src[off + i + 3];
        float v0 = s[(size_t)p0 * 8 + c];
        float v1 = s[(size_t)p1 * 8 + c];
        float v2 = s[(size_t)p2 * 8 + c];
        float v3 = s[(size_t)p3 * 8 + c];
        acc += (v0 + v1) + (v2 + v3);
    }
    for (; i < dg; ++i) acc += s[(size_t)csr_src[off + i] * 8 + c];
    acc *= 1.0f / (1.0f + (float)dg);
    if (c < 4) aggl[(size_t)n * 4 + c]     = acc;
    else       aggr[(size_t)n * 4 + c - 4] = acc;
}

// ---------------------------------------------------------------------------
// Fused softmax + value aggregation — v5 (unchanged).
// ---------------------------------------------------------------------------
template<int SZ>
__device__ __forceinline__ void gather_sub(int cs, float w, int base, int grp, int lof,
    const _Float16* __restrict__ xv,
    float& o0, float& o1, float& o2, float& o3)
{
    half4v hv[SZ];
#pragma unroll
    for (int j = 0; j < SZ; ++j) {
        int sidx = __builtin_amdgcn_readlane(cs, base + j);   // SGPR row index
        hv[j] = *(const half4v*)(xv + (((unsigned)sidx << 8) + lof));
    }
#pragma unroll
    for (int j = 0; j < SZ; ++j) {
        float wv = __shfl(w, grp + base + j, 64);
        o0 += wv * (float)hv[j][0];
        o1 += wv * (float)hv[j][1];
        o2 += wv * (float)hv[j][2];
        o3 += wv * (float)hv[j][3];
    }
}

__device__ __forceinline__ void do_chunk(int cs, float w, int cnt, int grp, int lof,
    const _Float16* __restrict__ xv,
    float& o0, float& o1, float& o2, float& o3)
{
    if (cnt == 16) { gather_sub<16>(cs, w, 0, grp, lof, xv, o0, o1, o2, o3); return; }
    int b = 0;
    if (cnt & 8) { gather_sub<8>(cs, w, b, grp, lof, xv, o0, o1, o2, o3); b += 8; }
    if (cnt & 4) { gather_sub<4>(cs, w, b, grp, lof, xv, o0, o1, o2, o3); b += 4; }
    if (cnt & 2) { gather_sub<2>(cs, w, b, grp, lof, xv, o0, o1, o2, o3); b += 2; }
    if (cnt & 1) { gather_sub<1>(cs, w, b, grp, lof, xv, o0, o1, o2, o3); }
}

__global__ __launch_bounds__(256) void attn_out(const float* __restrict__ aggl,
    const float* __restrict__ aggr, const int* __restrict__ csr_src,
    const int* __restrict__ offs, const int* __restrict__ deg,
    const _Float16* __restrict__ xv, float* __restrict__ out, int N)
{
    int wid = threadIdx.x >> 6, lane = threadIdx.x & 63;
    int n = blockIdx.x * 4 + wid;
    if (n >= N) return;
    int myhead = lane >> 4, myedge = lane & 15, grp = lane & 48;
    int lof = lane << 2;
    int off = offs[n], dg = deg[n];
    const int* cb = csr_src + off;
    float ar = aggr[(unsigned)(n * 4 + myhead)];

    float o0 = 0.f, o1 = 0.f, o2 = 0.f, o3 = 0.f;

    // ---- Phase A: all weight-phase loads issued upfront (independent). ----
    int cs0 = 0, cs1 = 0, cs2 = 0, cs3 = 0;
    int e1 = myedge + 16, e2 = myedge + 32, e3 = myedge + 48;
    if (myedge < dg) cs0 = cb[myedge];
    if (e1 < dg)     cs1 = cb[e1];
    if (e2 < dg)     cs2 = cb[e2];
    if (e3 < dg)     cs3 = cb[e3];
    float a0 = 0.f, a1 = 0.f, a2 = 0.f, a3 = 0.f;
    if (myedge < dg) a0 = aggl[(unsigned)((cs0 << 2) + myhead)];
    if (e1 < dg)     a1 = aggl[(unsigned)((cs1 << 2) + myhead)];
    if (e2 < dg)     a2 = aggl[(unsigned)((cs2 << 2) + myhead)];
    if (e3 < dg)     a3 = aggl[(unsigned)((cs3 << 2) + myhead)];
    float w0 = 0.f, w1 = 0.f, w2 = 0.f, w3 = 0.f;
    if (myedge < dg) { float e = a0 + ar; e = (e > 0.f) ? e : NEG_SLOPE * e; w0 = __expf(e); }
    if (e1 < dg)     { float e = a1 + ar; e = (e > 0.f) ? e : NEG_SLOPE * e; w1 = __expf(e); }
    if (e2 < dg)     { float e = a2 + ar; e = (e > 0.f) ? e : NEG_SLOPE * e; w2 = __expf(e); }
    if (e3 < dg)     { float e = a3 + ar; e = (e > 0.f) ? e : NEG_SLOPE * e; w3 = __expf(e); }
    float denom = w0; denom += w1; denom += w2; denom += w3;

    // ---- Phase B: gather rounds, weights already in registers. ----
    int c0 = dg < 16 ? dg : 16;
    do_chunk(cs0, w0, c0, grp, lof, xv, o0, o1, o2, o3);
    if (dg > 16) {
        int c1 = dg - 16 < 16 ? dg - 16 : 16;
        do_chunk(cs1, w1, c1, grp, lof, xv, o0, o1, o2, o3);
    }
    if (dg > 32) {
        int c2 = dg - 32 < 16 ? dg - 32 : 16;
        do_chunk(cs2, w2, c2, grp, lof, xv, o0, o1, o2, o3);
    }
    if (dg > 48) {
        int c3 = dg - 48 < 16 ? dg - 48 : 16;
        do_chunk(cs3, w3, c3, grp, lof, xv, o0, o1, o2, o3);
    }
    // Fallback for dg > 64 (essentially never for Poisson(16); correctness).
    for (int b = 64; b < dg; b += 16) {
        int cs = 0; float w = 0.f;
        if (b + myedge < dg) {
            cs = cb[b + myedge];
            float e = aggl[(unsigned)((cs << 2) + myhead)] + ar;
            e = (e > 0.f) ? e : NEG_SLOPE * e;
            w = __expf(e);
        }
        denom += w;
        int cnt = dg - b < 16 ? dg - b : 16;
        do_chunk(cs, w, cnt, grp, lof, xv, o0, o1, o2, o3);
    }

    // Sum denom over the 16 lanes of this head group.
#pragma unroll
    for (int o = 1; o <= 8; o <<= 1) denom += __shfl_xor(denom, o, 64);
    float inv = 1.0f / fmaxf(denom, 1e-16f);
    floatx4 res = {o0 * inv, o1 * inv, o2 * inv, o3 * inv};
    __builtin_nontemporal_store(res, (floatx4*)(out + (size_t)n * 256 + lof));
}

// ---------------------------------------------------------------------------
extern "C" void kernel_launch(void* const* d_in, const int* in_sizes, int n_in,
                              void* d_out, int out_size, void* d_ws, size_t ws_size,
                              hipStream_t stream)
{
    const float* x    = (const float*)d_in[0];
    const int*   src  = (const int*)d_in[1];
    const int*   dst  = (const int*)d_in[2];
    const float* Wl   = (const float*)d_in[3];
    const float* bl   = (const float*)d_in[4];
    const float* Wr   = (const float*)d_in[5];
    const float* br   = (const float*)d_in[6];
    const float* Wv   = (const float*)d_in[7];
    const float* bv   = (const float*)d_in[8];
    const float* attl = (const float*)d_in[9];
    const float* attr = (const float*)d_in[10];
    float* out = (float*)d_out;

    int N = in_sizes[0] / C_IN;
    int E = in_sizes[1];

    char* p = (char*)d_ws;
    auto alloc = [&](size_t bytes) -> void* {
        uintptr_t q = (uintptr_t)p;
        q = (q + 255) & ~(uintptr_t)255;
        p = (char*)(q + bytes);
        return (void*)q;
    };
    float* Ws     = (float*)alloc((size_t)C_IN * 8 * sizeof(float));
    float* bs     = (float*)alloc(8 * sizeof(float));
    float* s      = (float*)alloc((size_t)N * 8 * sizeof(float));
    float* aggl   = (float*)alloc((size_t)N * 4 * sizeof(float));
    float* aggr   = (float*)alloc((size_t)N * 4 * sizeof(float));
    int* deg      = (int*)alloc((size_t)N * sizeof(int));
    int* offs     = (int*)alloc((size_t)(N + 1) * sizeof(int));
    int* cursor   = (int*)alloc((size_t)N * sizeof(int));
    int* partials = (int*)alloc(256 * sizeof(int));
    int* pscan    = (int*)alloc(256 * sizeof(int));
    int* csr_src  = (int*)alloc((size_t)E * sizeof(int));
    _Float16* WvT = (_Float16*)alloc((size_t)C_IN * C_OUT * sizeof(_Float16));
    _Float16* xv  = (_Float16*)alloc((size_t)N * C_OUT * sizeof(_Float16));

    hipMemsetAsync(deg, 0, (size_t)N * sizeof(int), stream);
    hipMemsetAsync(cursor, 0, (size_t)N * sizeof(int), stream);

    make_eff_w<<<C_IN + 1, 256, 0, stream>>>(Wl, Wr, bl, br, attl, attr, Ws, bs);
    transpose_w<<<(C_IN * C_OUT) / 256, 256, 0, stream>>>(Wv, WvT);
    gemm_xv<<<dim3((N + 127) / 128, C_OUT / 64), 256, 0, stream>>>(x, WvT, bv, Ws, bs, xv, s, N);
    deg_kernel<<<((E + 3) / 4 + 255) / 256, 256, 0, stream>>>(dst, deg, E);
    int chunk = (N + 255) / 256;
    scan_part<<<256, 256, 0, stream>>>(deg, partials, N, chunk);
    scan_partials<<<1, 256, 0, stream>>>(partials, pscan);
    scan_final<<<256, 256, 0, stream>>>(deg, pscan, offs, N, chunk);
    scatter_kernel<<<((E + 3) / 4 + 255) / 256, 256, 0, stream>>>(src, dst, offs, cursor, csr_src, E);
    agg_kernel<<<(N * 8 + 255) / 256, 256, 0, stream>>>(s, csr_src, offs, deg, aggl, aggr, N);
    attn_out<<<(N + 3) / 4, 256, 0, stream>>>(aggl, aggr, csr_src, offs, deg, xv, out, N);
}

// Round 10
// 321.484 us; speedup vs baseline: 1.1817x; 1.0647x over previous
//
#include <hip/hip_runtime.h>

#define C_IN 256
#define C_OUT 256
#define NH 4
#define HD 64
#define NEG_SLOPE 0.2f

typedef _Float16 half8 __attribute__((ext_vector_type(8)));
typedef _Float16 half4v __attribute__((ext_vector_type(4)));
typedef float floatx4 __attribute__((ext_vector_type(4)));

// ---------------------------------------------------------------------------
// PREP (merged): blocks [0,256] = make_eff_w; [257,512] = transpose_w;
// [513,1294] = deg. All three are independent; branch by blockIdx only.
// Logic of each section is instruction-identical to the previous kernels.
// ---------------------------------------------------------------------------
__global__ void prep_kernel(const float* __restrict__ Wl, const float* __restrict__ Wr,
                            const float* __restrict__ bl, const float* __restrict__ br,
                            const float* __restrict__ attl, const float* __restrict__ attr,
                            const float* __restrict__ Wv, const int* __restrict__ dst,
                            float* __restrict__ Ws, float* __restrict__ bs,
                            _Float16* __restrict__ WvT, int* __restrict__ deg, int E)
{
    int bid = blockIdx.x;
    int t = threadIdx.x;
    if (bid <= C_IN) {
        // ---- make_eff_w ----
        int c = bid;
        int h = t >> 6, d = t & 63;
        float al = attl[t], ar = attr[t];
        float vl, vr;
        if (c < C_IN) { vl = Wl[c * C_OUT + t] * al; vr = Wr[c * C_OUT + t] * ar; }
        else          { vl = bl[t] * al;             vr = br[t] * ar; }
#pragma unroll
        for (int off = 32; off >= 1; off >>= 1) {
            vl += __shfl_xor(vl, off, 64);
            vr += __shfl_xor(vr, off, 64);
        }
        if (d == 0) {
            if (c < C_IN) { Ws[c * 8 + h] = vl; Ws[c * 8 + 4 + h] = vr; }
            else          { bs[h] = vl;         bs[4 + h] = vr; }
        }
    } else if (bid <= C_IN + 256) {
        // ---- transpose_w ----
        int idx = (bid - (C_IN + 1)) * 256 + t;
        int n = idx >> 8, k = idx & 255;
        WvT[n * 256 + k] = (_Float16)Wv[k * 256 + n];
    } else {
        // ---- deg (4 edges/thread, int4) ----
        int i = (bid - (C_IN + 257)) * 256 + t;
        int base = i * 4;
        if (base >= E) return;
        if (base + 4 <= E) {
            int4 d4 = *(const int4*)(dst + base);
            atomicAdd(&deg[d4.x], 1);
            atomicAdd(&deg[d4.y], 1);
            atomicAdd(&deg[d4.z], 1);
            atomicAdd(&deg[d4.w], 1);
        } else {
            for (int k = base; k < E; ++k) atomicAdd(&deg[dst[k]], 1);
        }
    }
}

// ---------------------------------------------------------------------------
// GEMM: exact v6 (proven 66.5 us): 128x128 tile, BK=32, LDS-staged A+B,
// fused node_scores on y==0, packed 8B As staging store.
// ---------------------------------------------------------------------------
__global__ __launch_bounds__(256) void gemm_xv(const float* __restrict__ x,
    const _Float16* __restrict__ WvT, const float* __restrict__ bv,
    const float* __restrict__ Ws, const float* __restrict__ bs,
    _Float16* __restrict__ xv, float* __restrict__ s, int M)
{
    __shared__ __align__(16) _Float16 As[128][40];
    __shared__ __align__(16) _Float16 Bs[128][40];
    int tid = threadIdx.x;
    int wid = tid >> 6, lane = tid & 63;
    int quad = lane >> 4, r16 = lane & 15;
    int m0 = blockIdx.x * 128, n0 = blockIdx.y * 128;
    bool do_s = (blockIdx.y == 0);

    floatx4 acc[2][8];
#pragma unroll
    for (int i = 0; i < 2; ++i)
#pragma unroll
        for (int j = 0; j < 8; ++j) acc[i][j] = (floatx4){0.f, 0.f, 0.f, 0.f};

    int arow = tid >> 3, af4 = tid & 7;
    int brow = tid >> 2, bg  = tid & 3;

    float sacc[4][8];
#pragma unroll
    for (int p = 0; p < 4; ++p)
#pragma unroll
        for (int j = 0; j < 8; ++j) sacc[p][j] = 0.f;

    for (int k0 = 0; k0 < 256; k0 += 32) {
        float w8[4][8];
        if (do_s) {
#pragma unroll
            for (int q = 0; q < 4; ++q) {
                const float4* wr = (const float4*)(Ws + (size_t)(k0 + af4 * 4 + q) * 8);
                float4 wa = wr[0], wb = wr[1];
                w8[q][0] = wa.x; w8[q][1] = wa.y; w8[q][2] = wa.z; w8[q][3] = wa.w;
                w8[q][4] = wb.x; w8[q][5] = wb.y; w8[q][6] = wb.z; w8[q][7] = wb.w;
            }
        }
#pragma unroll
        for (int p = 0; p < 4; ++p) {
            int rr = arow + p * 32;
            int gm = m0 + rr;
            float4 v = make_float4(0.f, 0.f, 0.f, 0.f);
            if (gm < M) v = *(const float4*)(x + (size_t)gm * 256 + k0 + af4 * 4);
            half4v tmp;
            tmp[0] = (_Float16)v.x; tmp[1] = (_Float16)v.y;
            tmp[2] = (_Float16)v.z; tmp[3] = (_Float16)v.w;
            *(half4v*)&As[rr][af4 * 4] = tmp;
            if (do_s) {
                float xq[4] = {v.x, v.y, v.z, v.w};
#pragma unroll
                for (int q = 0; q < 4; ++q)
#pragma unroll
                    for (int j = 0; j < 8; ++j)
                        sacc[p][j] += xq[q] * w8[q][j];
            }
        }
#pragma unroll
        for (int p = 0; p < 2; ++p) {
            int nr = brow + p * 64;
            *(float4*)&Bs[nr][bg * 8] = *(const float4*)(WvT + (size_t)(n0 + nr) * 256 + k0 + bg * 8);
        }
        __syncthreads();
        half8 a[2], b[8];
#pragma unroll
        for (int rg = 0; rg < 2; ++rg)
            a[rg] = *(const half8*)&As[wid * 32 + rg * 16 + r16][quad * 8];
#pragma unroll
        for (int cg = 0; cg < 8; ++cg)
            b[cg] = *(const half8*)&Bs[cg * 16 + r16][quad * 8];
#pragma unroll
        for (int rg = 0; rg < 2; ++rg)
#pragma unroll
            for (int cg = 0; cg < 8; ++cg)
                acc[rg][cg] = __builtin_amdgcn_mfma_f32_16x16x32_f16(a[rg], b[cg], acc[rg][cg], 0, 0, 0);
        __syncthreads();
    }

    if (do_s) {
        float b0[8];
#pragma unroll
        for (int j = 0; j < 8; ++j) b0[j] = bs[j];
#pragma unroll
        for (int p = 0; p < 4; ++p) {
#pragma unroll
            for (int o = 1; o <= 4; o <<= 1)
#pragma unroll
                for (int j = 0; j < 8; ++j)
                    sacc[p][j] += __shfl_xor(sacc[p][j], o, 64);
            int gm = m0 + arow + p * 32;
            if (af4 == 0 && gm < M) {
                *(float4*)(s + (size_t)gm * 8)     = make_float4(sacc[p][0] + b0[0], sacc[p][1] + b0[1], sacc[p][2] + b0[2], sacc[p][3] + b0[3]);
                *(float4*)(s + (size_t)gm * 8 + 4) = make_float4(sacc[p][4] + b0[4], sacc[p][5] + b0[5], sacc[p][6] + b0[6], sacc[p][7] + b0[7]);
            }
        }
    }

#pragma unroll
    for (int rg = 0; rg < 2; ++rg) {
        int rbase = m0 + wid * 32 + rg * 16 + quad * 4;
#pragma unroll
        for (int cg = 0; cg < 8; ++cg) {
            int gcol = n0 + cg * 16 + r16;
            float bias = bv[gcol];
#pragma unroll
            for (int rr = 0; rr < 4; ++rr) {
                int grow = rbase + rr;
                if (grow < M)
                    xv[(size_t)grow * 256 + gcol] = (_Float16)(acc[rg][cg][rr] + bias);
            }
        }
    }
}

// ---------------------------------------------------------------------------
// CSR scans. scan_part unchanged; scan_final now folds the partials scan
// (each of its 256 blocks redundantly scans the 256 partials in LDS --
// removes the scan_partials dispatch and its dependency link).
// ---------------------------------------------------------------------------
__global__ void scan_part(const int* __restrict__ deg, int* __restrict__ partials,
                          int N, int chunk)
{
    __shared__ int sd[256];
    int b = blockIdx.x, t = threadIdx.x;
    int idx = b * chunk + t;
    int v = (t < chunk && idx < N) ? deg[idx] : 0;
    sd[t] = v; __syncthreads();
    for (int off = 128; off >= 1; off >>= 1) {
        if (t < off) sd[t] += sd[t + off];
        __syncthreads();
    }
    if (t == 0) partials[b] = sd[0];
}

__global__ void scan_final(const int* __restrict__ deg, const int* __restrict__ partials,
                           int* __restrict__ offs, int N, int chunk)
{
    __shared__ int sp[256];
    __shared__ int sd[256];
    int b = blockIdx.x, t = threadIdx.x;
    // local exclusive-scan of the 256 partials (identical math to old scan_partials)
    int pv = partials[t];
    sp[t] = pv; __syncthreads();
    for (int off = 1; off < 256; off <<= 1) {
        int x = (t >= off) ? sp[t - off] : 0;
        __syncthreads();
        sp[t] += x;
        __syncthreads();
    }
    int base = sp[b] - partials[b];   // exclusive prefix at b
    __syncthreads();

    int idx = b * chunk + t;
    int v = (t < chunk && idx < N) ? deg[idx] : 0;
    sd[t] = v; __syncthreads();
    for (int off = 1; off < 256; off <<= 1) {
        int x = (t >= off) ? sd[t - off] : 0;
        __syncthreads();
        sd[t] += x;
        __syncthreads();
    }
    int incl = sd[t], excl = incl - v;
    if (t < chunk && idx < N) offs[idx] = base + excl;
    if (idx == N - 1) offs[N] = base + incl;  // == E
}

__global__ void scatter_kernel(const int* __restrict__ src, const int* __restrict__ dst,
                               const int* __restrict__ offs, int* __restrict__ cursor,
                               int* __restrict__ csr_src, int E)
{
    int i = blockIdx.x * 256 + threadIdx.x;
    int base = i * 4;
    if (base >= E) return;
    if (base + 4 <= E) {
        int4 d  = *(const int4*)(dst + base);
        int4 sv = *(const int4*)(src + base);
        int p0 = offs[d.x] + atomicAdd(&cursor[d.x], 1); csr_src[p0] = sv.x;
        int p1 = offs[d.y] + atomicAdd(&cursor[d.y], 1); csr_src[p1] = sv.y;
        int p2 = offs[d.z] + atomicAdd(&cursor[d.z], 1); csr_src[p2] = sv.z;
        int p3 = offs[d.w] + atomicAdd(&cursor[d.w], 1); csr_src[p3] = sv.w;
    } else {
        for (int k = base; k < E; ++k) {
            int d = dst[k];
            int p = offs[d] + atomicAdd(&cursor[d], 1);
            csr_src[p] = src[k];
        }
    }
}

// ---------------------------------------------------------------------------
// agg = (hlr + segsum(hlr[src] by dst)) / (1+deg). EIGHT threads per node.
// ---------------------------------------------------------------------------
__global__ void agg_kernel(const float* __restrict__ s, const int* __restrict__ csr_src,
                           const int* __restrict__ offs, const int* __restrict__ deg,
                           float* __restrict__ aggl, float* __restrict__ aggr, int N)
{
    int gid = blockIdx.x * 256 + threadIdx.x;
    int n = gid >> 3, c = gid & 7;
    if (n >= N) return;
    int off = offs[n], dg = deg[n];
    float acc = s[(size_t)n * 8 + c];
    int i = 0;
    for (; i + 4 <= dg; i += 4) {
        int p0 = csr_src[off + i];
        int p1 = csr_src[off + i + 1];
        int p2 = csr_src[off + i + 2];
        int p3 = csr_src[off + i + 3];
        float v0 = s[(size_t)p0 * 8 + c];
        float v1 = s[(size_t)p1 * 8 + c];
        float v2 = s[(size_t)p2 * 8 + c];
        float v3 = s[(size_t)p3 * 8 + c];
        acc += (v0 + v1) + (v2 + v3);
    }
    for (; i < dg; ++i) acc += s[(size_t)csr_src[off + i] * 8 + c];
    acc *= 1.0f / (1.0f + (float)dg);
    if (c < 4) aggl[(size_t)n * 4 + c]     = acc;
    else       aggr[(size_t)n * 4 + c - 4] = acc;
}

// ---------------------------------------------------------------------------
// Fused softmax + value aggregation — v5 (unchanged).
// ---------------------------------------------------------------------------
template<int SZ>
__device__ __forceinline__ void gather_sub(int cs, float w, int base, int grp, int lof,
    const _Float16* __restrict__ xv,
    float& o0, float& o1, float& o2, float& o3)
{
    half4v hv[SZ];
#pragma unroll
    for (int j = 0; j < SZ; ++j) {
        int sidx = __builtin_amdgcn_readlane(cs, base + j);   // SGPR row index
        hv[j] = *(const half4v*)(xv + (((unsigned)sidx << 8) + lof));
    }
#pragma unroll
    for (int j = 0; j < SZ; ++j) {
        float wv = __shfl(w, grp + base + j, 64);
        o0 += wv * (float)hv[j][0];
        o1 += wv * (float)hv[j][1];
        o2 += wv * (float)hv[j][2];
        o3 += wv * (float)hv[j][3];
    }
}

__device__ __forceinline__ void do_chunk(int cs, float w, int cnt, int grp, int lof,
    const _Float16* __restrict__ xv,
    float& o0, float& o1, float& o2, float& o3)
{
    if (cnt == 16) { gather_sub<16>(cs, w, 0, grp, lof, xv, o0, o1, o2, o3); return; }
    int b = 0;
    if (cnt & 8) { gather_sub<8>(cs, w, b, grp, lof, xv, o0, o1, o2, o3); b += 8; }
    if (cnt & 4) { gather_sub<4>(cs, w, b, grp, lof, xv, o0, o1, o2, o3); b += 4; }
    if (cnt & 2) { gather_sub<2>(cs, w, b, grp, lof, xv, o0, o1, o2, o3); b += 2; }
    if (cnt & 1) { gather_sub<1>(cs, w, b, grp, lof, xv, o0, o1, o2, o3); }
}

__global__ __launch_bounds__(256) void attn_out(const float* __restrict__ aggl,
    const float* __restrict__ aggr, const int* __restrict__ csr_src,
    const int* __restrict__ offs, const int* __restrict__ deg,
    const _Float16* __restrict__ xv, float* __restrict__ out, int N)
{
    int wid = threadIdx.x >> 6, lane = threadIdx.x & 63;
    int n = blockIdx.x * 4 + wid;
    if (n >= N) return;
    int myhead = lane >> 4, myedge = lane & 15, grp = lane & 48;
    int lof = lane << 2;
    int off = offs[n], dg = deg[n];
    const int* cb = csr_src + off;
    float ar = aggr[(unsigned)(n * 4 + myhead)];

    float o0 = 0.f, o1 = 0.f, o2 = 0.f, o3 = 0.f;

    int cs0 = 0, cs1 = 0, cs2 = 0, cs3 = 0;
    int e1 = myedge + 16, e2 = myedge + 32, e3 = myedge + 48;
    if (myedge < dg) cs0 = cb[myedge];
    if (e1 < dg)     cs1 = cb[e1];
    if (e2 < dg)     cs2 = cb[e2];
    if (e3 < dg)     cs3 = cb[e3];
    float a0 = 0.f, a1 = 0.f, a2 = 0.f, a3 = 0.f;
    if (myedge < dg) a0 = aggl[(unsigned)((cs0 << 2) + myhead)];
    if (e1 < dg)     a1 = aggl[(unsigned)((cs1 << 2) + myhead)];
    if (e2 < dg)     a2 = aggl[(unsigned)((cs2 << 2) + myhead)];
    if (e3 < dg)     a3 = aggl[(unsigned)((cs3 << 2) + myhead)];
    float w0 = 0.f, w1 = 0.f, w2 = 0.f, w3 = 0.f;
    if (myedge < dg) { float e = a0 + ar; e = (e > 0.f) ? e : NEG_SLOPE * e; w0 = __expf(e); }
    if (e1 < dg)     { float e = a1 + ar; e = (e > 0.f) ? e : NEG_SLOPE * e; w1 = __expf(e); }
    if (e2 < dg)     { float e = a2 + ar; e = (e > 0.f) ? e : NEG_SLOPE * e; w2 = __expf(e); }
    if (e3 < dg)     { float e = a3 + ar; e = (e > 0.f) ? e : NEG_SLOPE * e; w3 = __expf(e); }
    float denom = w0; denom += w1; denom += w2; denom += w3;

    int c0 = dg < 16 ? dg : 16;
    do_chunk(cs0, w0, c0, grp, lof, xv, o0, o1, o2, o3);
    if (dg > 16) {
        int c1 = dg - 16 < 16 ? dg - 16 : 16;
        do_chunk(cs1, w1, c1, grp, lof, xv, o0, o1, o2, o3);
    }
    if (dg > 32) {
        int c2 = dg - 32 < 16 ? dg - 32 : 16;
        do_chunk(cs2, w2, c2, grp, lof, xv, o0, o1, o2, o3);
    }
    if (dg > 48) {
        int c3 = dg - 48 < 16 ? dg - 48 : 16;
        do_chunk(cs3, w3, c3, grp, lof, xv, o0, o1, o2, o3);
    }
    for (int b = 64; b < dg; b += 16) {
        int cs = 0; float w = 0.f;
        if (b + myedge < dg) {
            cs = cb[b + myedge];
            float e = aggl[(unsigned)((cs << 2) + myhead)] + ar;
            e = (e > 0.f) ? e : NEG_SLOPE * e;
            w = __expf(e);
        }
        denom += w;
        int cnt = dg - b < 16 ? dg - b : 16;
        do_chunk(cs, w, cnt, grp, lof, xv, o0, o1, o2, o3);
    }

#pragma unroll
    for (int o = 1; o <= 8; o <<= 1) denom += __shfl_xor(denom, o, 64);
    float inv = 1.0f / fmaxf(denom, 1e-16f);
    floatx4 res = {o0 * inv, o1 * inv, o2 * inv, o3 * inv};
    __builtin_nontemporal_store(res, (floatx4*)(out + (size_t)n * 256 + lof));
}

// ---------------------------------------------------------------------------
extern "C" void kernel_launch(void* const* d_in, const int* in_sizes, int n_in,
                              void* d_out, int out_size, void* d_ws, size_t ws_size,
                              hipStream_t stream)
{
    const float* x    = (const float*)d_in[0];
    const int*   src  = (const int*)d_in[1];
    const int*   dst  = (const int*)d_in[2];
    const float* Wl   = (const float*)d_in[3];
    const float* bl   = (const float*)d_in[4];
    const float* Wr   = (const float*)d_in[5];
    const float* br   = (const float*)d_in[6];
    const float* Wv   = (const float*)d_in[7];
    const float* bv   = (const float*)d_in[8];
    const float* attl = (const float*)d_in[9];
    const float* attr = (const float*)d_in[10];
    float* out = (float*)d_out;

    int N = in_sizes[0] / C_IN;
    int E = in_sizes[1];

    char* p = (char*)d_ws;
    auto alloc = [&](size_t bytes) -> void* {
        uintptr_t q = (uintptr_t)p;
        q = (q + 255) & ~(uintptr_t)255;
        p = (char*)(q + bytes);
        return (void*)q;
    };
    float* Ws     = (float*)alloc((size_t)C_IN * 8 * sizeof(float));
    float* bs     = (float*)alloc(8 * sizeof(float));
    float* s      = (float*)alloc((size_t)N * 8 * sizeof(float));
    float* aggl   = (float*)alloc((size_t)N * 4 * sizeof(float));
    float* aggr   = (float*)alloc((size_t)N * 4 * sizeof(float));
    int* deg      = (int*)alloc((size_t)N * sizeof(int));
    int* cursor   = (int*)alloc((size_t)N * sizeof(int));   // adjacent to deg
    int* offs     = (int*)alloc((size_t)(N + 1) * sizeof(int));
    int* partials = (int*)alloc(256 * sizeof(int));
    int* csr_src  = (int*)alloc((size_t)E * sizeof(int));
    _Float16* WvT = (_Float16*)alloc((size_t)C_IN * C_OUT * sizeof(_Float16));
    _Float16* xv  = (_Float16*)alloc((size_t)N * C_OUT * sizeof(_Float16));

    // One memset covers deg..cursor span (adjacent allocs; pad bytes harmless).
    size_t zspan = (size_t)((char*)cursor + (size_t)N * sizeof(int) - (char*)deg);
    hipMemsetAsync(deg, 0, zspan, stream);

    int deg_blocks = ((E + 3) / 4 + 255) / 256;
    prep_kernel<<<C_IN + 257 + deg_blocks, 256, 0, stream>>>(
        Wl, Wr, bl, br, attl, attr, Wv, dst, Ws, bs, WvT, deg, E);
    gemm_xv<<<dim3((N + 127) / 128, C_OUT / 128), 256, 0, stream>>>(x, WvT, bv, Ws, bs, xv, s, N);
    int chunk = (N + 255) / 256;
    scan_part<<<256, 256, 0, stream>>>(deg, partials, N, chunk);
    scan_final<<<256, 256, 0, stream>>>(deg, partials, offs, N, chunk);
    scatter_kernel<<<((E + 3) / 4 + 255) / 256, 256, 0, stream>>>(src, dst, offs, cursor, csr_src, E);
    agg_kernel<<<(N * 8 + 255) / 256, 256, 0, stream>>>(s, csr_src, offs, deg, aggl, aggr, N);
    attn_out<<<(N + 3) / 4, 256, 0, stream>>>(aggl, aggr, csr_src, offs, deg, xv, out, N);
}

// Round 11
// 296.295 us; speedup vs baseline: 1.2821x; 1.0850x over previous
//
#include <hip/hip_runtime.h>

#define C_IN 256
#define C_OUT 256
#define NH 4
#define HD 64
#define NEG_SLOPE 0.2f

typedef _Float16 half8 __attribute__((ext_vector_type(8)));
typedef _Float16 half4v __attribute__((ext_vector_type(4)));
typedef float floatx4 __attribute__((ext_vector_type(4)));

// ---------------------------------------------------------------------------
// PREP (merged): blocks [0,256] = make_eff_w; [257,512] = transpose_w;
// [513,...] = deg + RANK: atomicAdd's return value IS the edge's
// within-segment rank -> stored to rank[i] (sequential int4 write). This
// lets scatter run with ZERO atomics (cursor array deleted).
// ---------------------------------------------------------------------------
__global__ void prep_kernel(const float* __restrict__ Wl, const float* __restrict__ Wr,
                            const float* __restrict__ bl, const float* __restrict__ br,
                            const float* __restrict__ attl, const float* __restrict__ attr,
                            const float* __restrict__ Wv, const int* __restrict__ dst,
                            float* __restrict__ Ws, float* __restrict__ bs,
                            _Float16* __restrict__ WvT, int* __restrict__ deg,
                            int* __restrict__ rank, int E)
{
    int bid = blockIdx.x;
    int t = threadIdx.x;
    if (bid <= C_IN) {
        // ---- make_eff_w ----
        int c = bid;
        int h = t >> 6, d = t & 63;
        float al = attl[t], ar = attr[t];
        float vl, vr;
        if (c < C_IN) { vl = Wl[c * C_OUT + t] * al; vr = Wr[c * C_OUT + t] * ar; }
        else          { vl = bl[t] * al;             vr = br[t] * ar; }
#pragma unroll
        for (int off = 32; off >= 1; off >>= 1) {
            vl += __shfl_xor(vl, off, 64);
            vr += __shfl_xor(vr, off, 64);
        }
        if (d == 0) {
            if (c < C_IN) { Ws[c * 8 + h] = vl; Ws[c * 8 + 4 + h] = vr; }
            else          { bs[h] = vl;         bs[4 + h] = vr; }
        }
    } else if (bid <= C_IN + 256) {
        // ---- transpose_w ----
        int idx = (bid - (C_IN + 1)) * 256 + t;
        int n = idx >> 8, k = idx & 255;
        WvT[n * 256 + k] = (_Float16)Wv[k * 256 + n];
    } else {
        // ---- deg + rank (4 edges/thread, int4) ----
        int i = (bid - (C_IN + 257)) * 256 + t;
        int base = i * 4;
        if (base >= E) return;
        if (base + 4 <= E) {
            int4 d4 = *(const int4*)(dst + base);
            int r0 = atomicAdd(&deg[d4.x], 1);
            int r1 = atomicAdd(&deg[d4.y], 1);
            int r2 = atomicAdd(&deg[d4.z], 1);
            int r3 = atomicAdd(&deg[d4.w], 1);
            *(int4*)(rank + base) = make_int4(r0, r1, r2, r3);
        } else {
            for (int k = base; k < E; ++k) rank[k] = atomicAdd(&deg[dst[k]], 1);
        }
    }
}

// ---------------------------------------------------------------------------
// GEMM: exact v6 (proven 65.5 us): 128x128 tile, BK=32, LDS-staged A+B,
// fused node_scores on y==0, packed 8B As staging store.
// ---------------------------------------------------------------------------
__global__ __launch_bounds__(256) void gemm_xv(const float* __restrict__ x,
    const _Float16* __restrict__ WvT, const float* __restrict__ bv,
    const float* __restrict__ Ws, const float* __restrict__ bs,
    _Float16* __restrict__ xv, float* __restrict__ s, int M)
{
    __shared__ __align__(16) _Float16 As[128][40];
    __shared__ __align__(16) _Float16 Bs[128][40];
    int tid = threadIdx.x;
    int wid = tid >> 6, lane = tid & 63;
    int quad = lane >> 4, r16 = lane & 15;
    int m0 = blockIdx.x * 128, n0 = blockIdx.y * 128;
    bool do_s = (blockIdx.y == 0);

    floatx4 acc[2][8];
#pragma unroll
    for (int i = 0; i < 2; ++i)
#pragma unroll
        for (int j = 0; j < 8; ++j) acc[i][j] = (floatx4){0.f, 0.f, 0.f, 0.f};

    int arow = tid >> 3, af4 = tid & 7;
    int brow = tid >> 2, bg  = tid & 3;

    float sacc[4][8];
#pragma unroll
    for (int p = 0; p < 4; ++p)
#pragma unroll
        for (int j = 0; j < 8; ++j) sacc[p][j] = 0.f;

    for (int k0 = 0; k0 < 256; k0 += 32) {
        float w8[4][8];
        if (do_s) {
#pragma unroll
            for (int q = 0; q < 4; ++q) {
                const float4* wr = (const float4*)(Ws + (size_t)(k0 + af4 * 4 + q) * 8);
                float4 wa = wr[0], wb = wr[1];
                w8[q][0] = wa.x; w8[q][1] = wa.y; w8[q][2] = wa.z; w8[q][3] = wa.w;
                w8[q][4] = wb.x; w8[q][5] = wb.y; w8[q][6] = wb.z; w8[q][7] = wb.w;
            }
        }
#pragma unroll
        for (int p = 0; p < 4; ++p) {
            int rr = arow + p * 32;
            int gm = m0 + rr;
            float4 v = make_float4(0.f, 0.f, 0.f, 0.f);
            if (gm < M) v = *(const float4*)(x + (size_t)gm * 256 + k0 + af4 * 4);
            half4v tmp;
            tmp[0] = (_Float16)v.x; tmp[1] = (_Float16)v.y;
            tmp[2] = (_Float16)v.z; tmp[3] = (_Float16)v.w;
            *(half4v*)&As[rr][af4 * 4] = tmp;
            if (do_s) {
                float xq[4] = {v.x, v.y, v.z, v.w};
#pragma unroll
                for (int q = 0; q < 4; ++q)
#pragma unroll
                    for (int j = 0; j < 8; ++j)
                        sacc[p][j] += xq[q] * w8[q][j];
            }
        }
#pragma unroll
        for (int p = 0; p < 2; ++p) {
            int nr = brow + p * 64;
            *(float4*)&Bs[nr][bg * 8] = *(const float4*)(WvT + (size_t)(n0 + nr) * 256 + k0 + bg * 8);
        }
        __syncthreads();
        half8 a[2], b[8];
#pragma unroll
        for (int rg = 0; rg < 2; ++rg)
            a[rg] = *(const half8*)&As[wid * 32 + rg * 16 + r16][quad * 8];
#pragma unroll
        for (int cg = 0; cg < 8; ++cg)
            b[cg] = *(const half8*)&Bs[cg * 16 + r16][quad * 8];
#pragma unroll
        for (int rg = 0; rg < 2; ++rg)
#pragma unroll
            for (int cg = 0; cg < 8; ++cg)
                acc[rg][cg] = __builtin_amdgcn_mfma_f32_16x16x32_f16(a[rg], b[cg], acc[rg][cg], 0, 0, 0);
        __syncthreads();
    }

    if (do_s) {
        float b0[8];
#pragma unroll
        for (int j = 0; j < 8; ++j) b0[j] = bs[j];
#pragma unroll
        for (int p = 0; p < 4; ++p) {
#pragma unroll
            for (int o = 1; o <= 4; o <<= 1)
#pragma unroll
                for (int j = 0; j < 8; ++j)
                    sacc[p][j] += __shfl_xor(sacc[p][j], o, 64);
            int gm = m0 + arow + p * 32;
            if (af4 == 0 && gm < M) {
                *(float4*)(s + (size_t)gm * 8)     = make_float4(sacc[p][0] + b0[0], sacc[p][1] + b0[1], sacc[p][2] + b0[2], sacc[p][3] + b0[3]);
                *(float4*)(s + (size_t)gm * 8 + 4) = make_float4(sacc[p][4] + b0[4], sacc[p][5] + b0[5], sacc[p][6] + b0[6], sacc[p][7] + b0[7]);
            }
        }
    }

#pragma unroll
    for (int rg = 0; rg < 2; ++rg) {
        int rbase = m0 + wid * 32 + rg * 16 + quad * 4;
#pragma unroll
        for (int cg = 0; cg < 8; ++cg) {
            int gcol = n0 + cg * 16 + r16;
            float bias = bv[gcol];
#pragma unroll
            for (int rr = 0; rr < 4; ++rr) {
                int grow = rbase + rr;
                if (grow < M)
                    xv[(size_t)grow * 256 + gcol] = (_Float16)(acc[rg][cg][rr] + bias);
            }
        }
    }
}

// ---------------------------------------------------------------------------
// CSR scans (v10-proven: scan_part + folded-partials scan_final).
// ---------------------------------------------------------------------------
__global__ void scan_part(const int* __restrict__ deg, int* __restrict__ partials,
                          int N, int chunk)
{
    __shared__ int sd[256];
    int b = blockIdx.x, t = threadIdx.x;
    int idx = b * chunk + t;
    int v = (t < chunk && idx < N) ? deg[idx] : 0;
    sd[t] = v; __syncthreads();
    for (int off = 128; off >= 1; off >>= 1) {
        if (t < off) sd[t] += sd[t + off];
        __syncthreads();
    }
    if (t == 0) partials[b] = sd[0];
}

__global__ void scan_final(const int* __restrict__ deg, const int* __restrict__ partials,
                           int* __restrict__ offs, int N, int chunk)
{
    __shared__ int sp[256];
    __shared__ int sd[256];
    int b = blockIdx.x, t = threadIdx.x;
    int pv = partials[t];
    sp[t] = pv; __syncthreads();
    for (int off = 1; off < 256; off <<= 1) {
        int x = (t >= off) ? sp[t - off] : 0;
        __syncthreads();
        sp[t] += x;
        __syncthreads();
    }
    int base = sp[b] - partials[b];   // exclusive prefix at b
    __syncthreads();

    int idx = b * chunk + t;
    int v = (t < chunk && idx < N) ? deg[idx] : 0;
    sd[t] = v; __syncthreads();
    for (int off = 1; off < 256; off <<= 1) {
        int x = (t >= off) ? sd[t - off] : 0;
        __syncthreads();
        sd[t] += x;
        __syncthreads();
    }
    int incl = sd[t], excl = incl - v;
    if (t < chunk && idx < N) offs[idx] = base + excl;
    if (idx == N - 1) offs[N] = base + incl;  // == E
}

// ---------------------------------------------------------------------------
// Scatter v11: ZERO atomics. pos = offs[d] + rank[i] (rank from prep's
// atomicAdd return). Pure loads + one random 4B store per edge.
// ---------------------------------------------------------------------------
__global__ void scatter_kernel(const int* __restrict__ src, const int* __restrict__ dst,
                               const int* __restrict__ offs, const int* __restrict__ rank,
                               int* __restrict__ csr_src, int E)
{
    int i = blockIdx.x * 256 + threadIdx.x;
    int base = i * 4;
    if (base >= E) return;
    if (base + 4 <= E) {
        int4 d  = *(const int4*)(dst + base);
        int4 sv = *(const int4*)(src + base);
        int4 r  = *(const int4*)(rank + base);
        csr_src[offs[d.x] + r.x] = sv.x;
        csr_src[offs[d.y] + r.y] = sv.y;
        csr_src[offs[d.z] + r.z] = sv.z;
        csr_src[offs[d.w] + r.w] = sv.w;
    } else {
        for (int k = base; k < E; ++k)
            csr_src[offs[dst[k]] + rank[k]] = src[k];
    }
}

// ---------------------------------------------------------------------------
// agg = (hlr + segsum(hlr[src] by dst)) / (1+deg). EIGHT threads per node.
// ---------------------------------------------------------------------------
__global__ void agg_kernel(const float* __restrict__ s, const int* __restrict__ csr_src,
                           const int* __restrict__ offs, const int* __restrict__ deg,
                           float* __restrict__ aggl, float* __restrict__ aggr, int N)
{
    int gid = blockIdx.x * 256 + threadIdx.x;
    int n = gid >> 3, c = gid & 7;
    if (n >= N) return;
    int off = offs[n], dg = deg[n];
    float acc = s[(size_t)n * 8 + c];
    int i = 0;
    for (; i + 4 <= dg; i += 4) {
        int p0 = csr_src[off + i];
        int p1 = csr_src[off + i + 1];
        int p2 = csr_src[off + i + 2];
        int p3 = csr_src[off + i + 3];
        float v0 = s[(size_t)p0 * 8 + c];
        float v1 = s[(size_t)p1 * 8 + c];
        float v2 = s[(size_t)p2 * 8 + c];
        float v3 = s[(size_t)p3 * 8 + c];
        acc += (v0 + v1) + (v2 + v3);
    }
    for (; i < dg; ++i) acc += s[(size_t)csr_src[off + i] * 8 + c];
    acc *= 1.0f / (1.0f + (float)dg);
    if (c < 4) aggl[(size_t)n * 4 + c]     = acc;
    else       aggr[(size_t)n * 4 + c - 4] = acc;
}

// ---------------------------------------------------------------------------
// Fused softmax + value aggregation — v5 (unchanged).
// ---------------------------------------------------------------------------
template<int SZ>
__device__ __forceinline__ void gather_sub(int cs, float w, int base, int grp, int lof,
    const _Float16* __restrict__ xv,
    float& o0, float& o1, float& o2, float& o3)
{
    half4v hv[SZ];
#pragma unroll
    for (int j = 0; j < SZ; ++j) {
        int sidx = __builtin_amdgcn_readlane(cs, base + j);   // SGPR row index
        hv[j] = *(const half4v*)(xv + (((unsigned)sidx << 8) + lof));
    }
#pragma unroll
    for (int j = 0; j < SZ; ++j) {
        float wv = __shfl(w, grp + base + j, 64);
        o0 += wv * (float)hv[j][0];
        o1 += wv * (float)hv[j][1];
        o2 += wv * (float)hv[j][2];
        o3 += wv * (float)hv[j][3];
    }
}

__device__ __forceinline__ void do_chunk(int cs, float w, int cnt, int grp, int lof,
    const _Float16* __restrict__ xv,
    float& o0, float& o1, float& o2, float& o3)
{
    if (cnt == 16) { gather_sub<16>(cs, w, 0, grp, lof, xv, o0, o1, o2, o3); return; }
    int b = 0;
    if (cnt & 8) { gather_sub<8>(cs, w, b, grp, lof, xv, o0, o1, o2, o3); b += 8; }
    if (cnt & 4) { gather_sub<4>(cs, w, b, grp, lof, xv, o0, o1, o2, o3); b += 4; }
    if (cnt & 2) { gather_sub<2>(cs, w, b, grp, lof, xv, o0, o1, o2, o3); b += 2; }
    if (cnt & 1) { gather_sub<1>(cs, w, b, grp, lof, xv, o0, o1, o2, o3); }
}

__global__ __launch_bounds__(256) void attn_out(const float* __restrict__ aggl,
    const float* __restrict__ aggr, const int* __restrict__ csr_src,
    const int* __restrict__ offs, const int* __restrict__ deg,
    const _Float16* __restrict__ xv, float* __restrict__ out, int N)
{
    int wid = threadIdx.x >> 6, lane = threadIdx.x & 63;
    int n = blockIdx.x * 4 + wid;
    if (n >= N) return;
    int myhead = lane >> 4, myedge = lane & 15, grp = lane & 48;
    int lof = lane << 2;
    int off = offs[n], dg = deg[n];
    const int* cb = csr_src + off;
    float ar = aggr[(unsigned)(n * 4 + myhead)];

    float o0 = 0.f, o1 = 0.f, o2 = 0.f, o3 = 0.f;

    int cs0 = 0, cs1 = 0, cs2 = 0, cs3 = 0;
    int e1 = myedge + 16, e2 = myedge + 32, e3 = myedge + 48;
    if (myedge < dg) cs0 = cb[myedge];
    if (e1 < dg)     cs1 = cb[e1];
    if (e2 < dg)     cs2 = cb[e2];
    if (e3 < dg)     cs3 = cb[e3];
    float a0 = 0.f, a1 = 0.f, a2 = 0.f, a3 = 0.f;
    if (myedge < dg) a0 = aggl[(unsigned)((cs0 << 2) + myhead)];
    if (e1 < dg)     a1 = aggl[(unsigned)((cs1 << 2) + myhead)];
    if (e2 < dg)     a2 = aggl[(unsigned)((cs2 << 2) + myhead)];
    if (e3 < dg)     a3 = aggl[(unsigned)((cs3 << 2) + myhead)];
    float w0 = 0.f, w1 = 0.f, w2 = 0.f, w3 = 0.f;
    if (myedge < dg) { float e = a0 + ar; e = (e > 0.f) ? e : NEG_SLOPE * e; w0 = __expf(e); }
    if (e1 < dg)     { float e = a1 + ar; e = (e > 0.f) ? e : NEG_SLOPE * e; w1 = __expf(e); }
    if (e2 < dg)     { float e = a2 + ar; e = (e > 0.f) ? e : NEG_SLOPE * e; w2 = __expf(e); }
    if (e3 < dg)     { float e = a3 + ar; e = (e > 0.f) ? e : NEG_SLOPE * e; w3 = __expf(e); }
    float denom = w0; denom += w1; denom += w2; denom += w3;

    int c0 = dg < 16 ? dg : 16;
    do_chunk(cs0, w0, c0, grp, lof, xv, o0, o1, o2, o3);
    if (dg > 16) {
        int c1 = dg - 16 < 16 ? dg - 16 : 16;
        do_chunk(cs1, w1, c1, grp, lof, xv, o0, o1, o2, o3);
    }
    if (dg > 32) {
        int c2 = dg - 32 < 16 ? dg - 32 : 16;
        do_chunk(cs2, w2, c2, grp, lof, xv, o0, o1, o2, o3);
    }
    if (dg > 48) {
        int c3 = dg - 48 < 16 ? dg - 48 : 16;
        do_chunk(cs3, w3, c3, grp, lof, xv, o0, o1, o2, o3);
    }
    for (int b = 64; b < dg; b += 16) {
        int cs = 0; float w = 0.f;
        if (b + myedge < dg) {
            cs = cb[b + myedge];
            float e = aggl[(unsigned)((cs << 2) + myhead)] + ar;
            e = (e > 0.f) ? e : NEG_SLOPE * e;
            w = __expf(e);
        }
        denom += w;
        int cnt = dg - b < 16 ? dg - b : 16;
        do_chunk(cs, w, cnt, grp, lof, xv, o0, o1, o2, o3);
    }

#pragma unroll
    for (int o = 1; o <= 8; o <<= 1) denom += __shfl_xor(denom, o, 64);
    float inv = 1.0f / fmaxf(denom, 1e-16f);
    floatx4 res = {o0 * inv, o1 * inv, o2 * inv, o3 * inv};
    __builtin_nontemporal_store(res, (floatx4*)(out + (size_t)n * 256 + lof));
}

// ---------------------------------------------------------------------------
extern "C" void kernel_launch(void* const* d_in, const int* in_sizes, int n_in,
                              void* d_out, int out_size, void* d_ws, size_t ws_size,
                              hipStream_t stream)
{
    const float* x    = (const float*)d_in[0];
    const int*   src  = (const int*)d_in[1];
    const int*   dst  = (const int*)d_in[2];
    const float* Wl   = (const float*)d_in[3];
    const float* bl   = (const float*)d_in[4];
    const float* Wr   = (const float*)d_in[5];
    const float* br   = (const float*)d_in[6];
    const float* Wv   = (const float*)d_in[7];
    const float* bv   = (const float*)d_in[8];
    const float* attl = (const float*)d_in[9];
    const float* attr = (const float*)d_in[10];
    float* out = (float*)d_out;

    int N = in_sizes[0] / C_IN;
    int E = in_sizes[1];

    char* p = (char*)d_ws;
    auto alloc = [&](size_t bytes) -> void* {
        uintptr_t q = (uintptr_t)p;
        q = (q + 255) & ~(uintptr_t)255;
        p = (char*)(q + bytes);
        return (void*)q;
    };
    float* Ws     = (float*)alloc((size_t)C_IN * 8 * sizeof(float));
    float* bs     = (float*)alloc(8 * sizeof(float));
    float* s      = (float*)alloc((size_t)N * 8 * sizeof(float));
    float* aggl   = (float*)alloc((size_t)N * 4 * sizeof(float));
    float* aggr   = (float*)alloc((size_t)N * 4 * sizeof(float));
    int* deg      = (int*)alloc((size_t)N * sizeof(int));
    int* offs     = (int*)alloc((size_t)(N + 1) * sizeof(int));
    int* partials = (int*)alloc(256 * sizeof(int));
    int* csr_src  = (int*)alloc((size_t)E * sizeof(int));
    _Float16* WvT = (_Float16*)alloc((size_t)C_IN * C_OUT * sizeof(_Float16));
    _Float16* xv  = (_Float16*)alloc((size_t)N * C_OUT * sizeof(_Float16));

    // rank[i] lives in d_out: only attn_out writes out, AFTER scatter
    // consumed rank. E*4 = 3.2 MB << out_size = 51.2 MB.
    int* rank = (int*)d_out;

    hipMemsetAsync(deg, 0, (size_t)N * sizeof(int), stream);

    int deg_blocks = ((E + 3) / 4 + 255) / 256;
    prep_kernel<<<C_IN + 257 + deg_blocks, 256, 0, stream>>>(
        Wl, Wr, bl, br, attl, attr, Wv, dst, Ws, bs, WvT, deg, rank, E);
    gemm_xv<<<dim3((N + 127) / 128, C_OUT / 128), 256, 0, stream>>>(x, WvT, bv, Ws, bs, xv, s, N);
    int chunk = (N + 255) / 256;
    scan_part<<<256, 256, 0, stream>>>(deg, partials, N, chunk);
    scan_final<<<256, 256, 0, stream>>>(deg, partials, offs, N, chunk);
    scatter_kernel<<<((E + 3) / 4 + 255) / 256, 256, 0, stream>>>(src, dst, offs, rank, csr_src, E);
    agg_kernel<<<(N * 8 + 255) / 256, 256, 0, stream>>>(s, csr_src, offs, deg, aggl, aggr, N);
    attn_out<<<(N + 3) / 4, 256, 0, stream>>>(aggl, aggr, csr_src, offs, deg, xv, out, N);
}

// Round 12
// 286.030 us; speedup vs baseline: 1.3281x; 1.0359x over previous
//
#include <hip/hip_runtime.h>

#define C_IN 256
#define C_OUT 256
#define NH 4
#define HD 64
#define NEG_SLOPE 0.2f

typedef _Float16 half8 __attribute__((ext_vector_type(8)));
typedef _Float16 half4v __attribute__((ext_vector_type(4)));
typedef float floatx4 __attribute__((ext_vector_type(4)));

// ---------------------------------------------------------------------------
// PREP (merged): blocks [0,256] = make_eff_w; [257,512] = transpose_w;
// [513,...] = deg + RANK (atomicAdd return = within-segment rank).
// ---------------------------------------------------------------------------
__global__ void prep_kernel(const float* __restrict__ Wl, const float* __restrict__ Wr,
                            const float* __restrict__ bl, const float* __restrict__ br,
                            const float* __restrict__ attl, const float* __restrict__ attr,
                            const float* __restrict__ Wv, const int* __restrict__ dst,
                            float* __restrict__ Ws, float* __restrict__ bs,
                            _Float16* __restrict__ WvT, int* __restrict__ deg,
                            int* __restrict__ rank, int E)
{
    int bid = blockIdx.x;
    int t = threadIdx.x;
    if (bid <= C_IN) {
        int c = bid;
        int h = t >> 6, d = t & 63;
        float al = attl[t], ar = attr[t];
        float vl, vr;
        if (c < C_IN) { vl = Wl[c * C_OUT + t] * al; vr = Wr[c * C_OUT + t] * ar; }
        else          { vl = bl[t] * al;             vr = br[t] * ar; }
#pragma unroll
        for (int off = 32; off >= 1; off >>= 1) {
            vl += __shfl_xor(vl, off, 64);
            vr += __shfl_xor(vr, off, 64);
        }
        if (d == 0) {
            if (c < C_IN) { Ws[c * 8 + h] = vl; Ws[c * 8 + 4 + h] = vr; }
            else          { bs[h] = vl;         bs[4 + h] = vr; }
        }
    } else if (bid <= C_IN + 256) {
        int idx = (bid - (C_IN + 1)) * 256 + t;
        int n = idx >> 8, k = idx & 255;
        WvT[n * 256 + k] = (_Float16)Wv[k * 256 + n];
    } else {
        int i = (bid - (C_IN + 257)) * 256 + t;
        int base = i * 4;
        if (base >= E) return;
        if (base + 4 <= E) {
            int4 d4 = *(const int4*)(dst + base);
            int r0 = atomicAdd(&deg[d4.x], 1);
            int r1 = atomicAdd(&deg[d4.y], 1);
            int r2 = atomicAdd(&deg[d4.z], 1);
            int r3 = atomicAdd(&deg[d4.w], 1);
            *(int4*)(rank + base) = make_int4(r0, r1, r2, r3);
        } else {
            for (int k = base; k < E; ++k) rank[k] = atomicAdd(&deg[dst[k]], 1);
        }
    }
}

// ---------------------------------------------------------------------------
// GEMM v12: v6/v11 structure with M-tile 128 -> 64 (traffic-neutral grid
// double: y-count unchanged so x re-reads DON'T grow, unlike v9's N-split).
// 1564 blocks (6.1/CU), acc VGPRs halved, LDS 15.4 KB. Per-row summation
// order for s and xv identical to v11 -> bit-identical outputs.
// ---------------------------------------------------------------------------
__global__ __launch_bounds__(256) void gemm_xv(const float* __restrict__ x,
    const _Float16* __restrict__ WvT, const float* __restrict__ bv,
    const float* __restrict__ Ws, const float* __restrict__ bs,
    _Float16* __restrict__ xv, float* __restrict__ s, int M)
{
    __shared__ __align__(16) _Float16 As[64][40];
    __shared__ __align__(16) _Float16 Bs[128][40];
    int tid = threadIdx.x;
    int wid = tid >> 6, lane = tid & 63;
    int quad = lane >> 4, r16 = lane & 15;
    int m0 = blockIdx.x * 64, n0 = blockIdx.y * 128;
    bool do_s = (blockIdx.y == 0);

    floatx4 acc[8];
#pragma unroll
    for (int j = 0; j < 8; ++j) acc[j] = (floatx4){0.f, 0.f, 0.f, 0.f};

    int arow = tid >> 3, af4 = tid & 7;   // arow 0..31
    int brow = tid >> 2, bg  = tid & 3;   // brow 0..63

    float sacc[2][8];
#pragma unroll
    for (int p = 0; p < 2; ++p)
#pragma unroll
        for (int j = 0; j < 8; ++j) sacc[p][j] = 0.f;

    for (int k0 = 0; k0 < 256; k0 += 32) {
        float w8[4][8];
        if (do_s) {
#pragma unroll
            for (int q = 0; q < 4; ++q) {
                const float4* wr = (const float4*)(Ws + (size_t)(k0 + af4 * 4 + q) * 8);
                float4 wa = wr[0], wb = wr[1];
                w8[q][0] = wa.x; w8[q][1] = wa.y; w8[q][2] = wa.z; w8[q][3] = wa.w;
                w8[q][4] = wb.x; w8[q][5] = wb.y; w8[q][6] = wb.z; w8[q][7] = wb.w;
            }
        }
#pragma unroll
        for (int p = 0; p < 2; ++p) {
            int rr = arow + p * 32;
            int gm = m0 + rr;
            float4 v = make_float4(0.f, 0.f, 0.f, 0.f);
            if (gm < M) v = *(const float4*)(x + (size_t)gm * 256 + k0 + af4 * 4);
            half4v tmp;
            tmp[0] = (_Float16)v.x; tmp[1] = (_Float16)v.y;
            tmp[2] = (_Float16)v.z; tmp[3] = (_Float16)v.w;
            *(half4v*)&As[rr][af4 * 4] = tmp;
            if (do_s) {
                float xq[4] = {v.x, v.y, v.z, v.w};
#pragma unroll
                for (int q = 0; q < 4; ++q)
#pragma unroll
                    for (int j = 0; j < 8; ++j)
                        sacc[p][j] += xq[q] * w8[q][j];
            }
        }
#pragma unroll
        for (int p = 0; p < 2; ++p) {
            int nr = brow + p * 64;
            *(float4*)&Bs[nr][bg * 8] = *(const float4*)(WvT + (size_t)(n0 + nr) * 256 + k0 + bg * 8);
        }
        __syncthreads();
        half8 a = *(const half8*)&As[wid * 16 + r16][quad * 8];
        half8 b[8];
#pragma unroll
        for (int cg = 0; cg < 8; ++cg)
            b[cg] = *(const half8*)&Bs[cg * 16 + r16][quad * 8];
#pragma unroll
        for (int cg = 0; cg < 8; ++cg)
            acc[cg] = __builtin_amdgcn_mfma_f32_16x16x32_f16(a, b[cg], acc[cg], 0, 0, 0);
        __syncthreads();
    }

    if (do_s) {
        float b0[8];
#pragma unroll
        for (int j = 0; j < 8; ++j) b0[j] = bs[j];
#pragma unroll
        for (int p = 0; p < 2; ++p) {
#pragma unroll
            for (int o = 1; o <= 4; o <<= 1)
#pragma unroll
                for (int j = 0; j < 8; ++j)
                    sacc[p][j] += __shfl_xor(sacc[p][j], o, 64);
            int gm = m0 + arow + p * 32;
            if (af4 == 0 && gm < M) {
                *(float4*)(s + (size_t)gm * 8)     = make_float4(sacc[p][0] + b0[0], sacc[p][1] + b0[1], sacc[p][2] + b0[2], sacc[p][3] + b0[3]);
                *(float4*)(s + (size_t)gm * 8 + 4) = make_float4(sacc[p][4] + b0[4], sacc[p][5] + b0[5], sacc[p][6] + b0[6], sacc[p][7] + b0[7]);
            }
        }
    }

#pragma unroll
    for (int cg = 0; cg < 8; ++cg) {
        int gcol = n0 + cg * 16 + r16;
        float bias = bv[gcol];
        int rbase = m0 + wid * 16 + quad * 4;
#pragma unroll
        for (int rr = 0; rr < 4; ++rr) {
            int grow = rbase + rr;
            if (grow < M)
                xv[(size_t)grow * 256 + gcol] = (_Float16)(acc[cg][rr] + bias);
        }
    }
}

// ---------------------------------------------------------------------------
// CSR scans (v10-proven).
// ---------------------------------------------------------------------------
__global__ void scan_part(const int* __restrict__ deg, int* __restrict__ partials,
                          int N, int chunk)
{
    __shared__ int sd[256];
    int b = blockIdx.x, t = threadIdx.x;
    int idx = b * chunk + t;
    int v = (t < chunk && idx < N) ? deg[idx] : 0;
    sd[t] = v; __syncthreads();
    for (int off = 128; off >= 1; off >>= 1) {
        if (t < off) sd[t] += sd[t + off];
        __syncthreads();
    }
    if (t == 0) partials[b] = sd[0];
}

__global__ void scan_final(const int* __restrict__ deg, const int* __restrict__ partials,
                           int* __restrict__ offs, int N, int chunk)
{
    __shared__ int sp[256];
    __shared__ int sd[256];
    int b = blockIdx.x, t = threadIdx.x;
    int pv = partials[t];
    sp[t] = pv; __syncthreads();
    for (int off = 1; off < 256; off <<= 1) {
        int x = (t >= off) ? sp[t - off] : 0;
        __syncthreads();
        sp[t] += x;
        __syncthreads();
    }
    int base = sp[b] - partials[b];   // exclusive prefix at b
    __syncthreads();

    int idx = b * chunk + t;
    int v = (t < chunk && idx < N) ? deg[idx] : 0;
    sd[t] = v; __syncthreads();
    for (int off = 1; off < 256; off <<= 1) {
        int x = (t >= off) ? sd[t - off] : 0;
        __syncthreads();
        sd[t] += x;
        __syncthreads();
    }
    int incl = sd[t], excl = incl - v;
    if (t < chunk && idx < N) offs[idx] = base + excl;
    if (idx == N - 1) offs[N] = base + incl;  // == E
}

// ---------------------------------------------------------------------------
// Scatter (v11-proven, zero atomics).
// ---------------------------------------------------------------------------
__global__ void scatter_kernel(const int* __restrict__ src, const int* __restrict__ dst,
                               const int* __restrict__ offs, const int* __restrict__ rank,
                               int* __restrict__ csr_src, int E)
{
    int i = blockIdx.x * 256 + threadIdx.x;
    int base = i * 4;
    if (base >= E) return;
    if (base + 4 <= E) {
        int4 d  = *(const int4*)(dst + base);
        int4 sv = *(const int4*)(src + base);
        int4 r  = *(const int4*)(rank + base);
        csr_src[offs[d.x] + r.x] = sv.x;
        csr_src[offs[d.y] + r.y] = sv.y;
        csr_src[offs[d.z] + r.z] = sv.z;
        csr_src[offs[d.w] + r.w] = sv.w;
    } else {
        for (int k = base; k < E; ++k)
            csr_src[offs[dst[k]] + rank[k]] = src[k];
    }
}

// ---------------------------------------------------------------------------
// agg = (hlr + segsum(hlr[src] by dst)) / (1+deg). EIGHT threads per node.
// ---------------------------------------------------------------------------
__global__ void agg_kernel(const float* __restrict__ s, const int* __restrict__ csr_src,
                           const int* __restrict__ offs, const int* __restrict__ deg,
                           float* __restrict__ aggl, float* __restrict__ aggr, int N)
{
    int gid = blockIdx.x * 256 + threadIdx.x;
    int n = gid >> 3, c = gid & 7;
    if (n >= N) return;
    int off = offs[n], dg = deg[n];
    float acc = s[(size_t)n * 8 + c];
    int i = 0;
    for (; i + 4 <= dg; i += 4) {
        int p0 = csr_src[off + i];
        int p1 = csr_src[off + i + 1];
        int p2 = csr_src[off + i + 2];
        int p3 = csr_src[off + i + 3];
        float v0 = s[(size_t)p0 * 8 + c];
        float v1 = s[(size_t)p1 * 8 + c];
        float v2 = s[(size_t)p2 * 8 + c];
        float v3 = s[(size_t)p3 * 8 + c];
        acc += (v0 + v1) + (v2 + v3);
    }
    for (; i < dg; ++i) acc += s[(size_t)csr_src[off + i] * 8 + c];
    acc *= 1.0f / (1.0f + (float)dg);
    if (c < 4) aggl[(size_t)n * 4 + c]     = acc;
    else       aggr[(size_t)n * 4 + c - 4] = acc;
}

// ---------------------------------------------------------------------------
// Fused softmax + value aggregation — v5 (unchanged).
// ---------------------------------------------------------------------------
template<int SZ>
__device__ __forceinline__ void gather_sub(int cs, float w, int base, int grp, int lof,
    const _Float16* __restrict__ xv,
    float& o0, float& o1, float& o2, float& o3)
{
    half4v hv[SZ];
#pragma unroll
    for (int j = 0; j < SZ; ++j) {
        int sidx = __builtin_amdgcn_readlane(cs, base + j);   // SGPR row index
        hv[j] = *(const half4v*)(xv + (((unsigned)sidx << 8) + lof));
    }
#pragma unroll
    for (int j = 0; j < SZ; ++j) {
        float wv = __shfl(w, grp + base + j, 64);
        o0 += wv * (float)hv[j][0];
        o1 += wv * (float)hv[j][1];
        o2 += wv * (float)hv[j][2];
        o3 += wv * (float)hv[j][3];
    }
}

__device__ __forceinline__ void do_chunk(int cs, float w, int cnt, int grp, int lof,
    const _Float16* __restrict__ xv,
    float& o0, float& o1, float& o2, float& o3)
{
    if (cnt == 16) { gather_sub<16>(cs, w, 0, grp, lof, xv, o0, o1, o2, o3); return; }
    int b = 0;
    if (cnt & 8) { gather_sub<8>(cs, w, b, grp, lof, xv, o0, o1, o2, o3); b += 8; }
    if (cnt & 4) { gather_sub<4>(cs, w, b, grp, lof, xv, o0, o1, o2, o3); b += 4; }
    if (cnt & 2) { gather_sub<2>(cs, w, b, grp, lof, xv, o0, o1, o2, o3); b += 2; }
    if (cnt & 1) { gather_sub<1>(cs, w, b, grp, lof, xv, o0, o1, o2, o3); }
}

__global__ __launch_bounds__(256) void attn_out(const float* __restrict__ aggl,
    const float* __restrict__ aggr, const int* __restrict__ csr_src,
    const int* __restrict__ offs, const int* __restrict__ deg,
    const _Float16* __restrict__ xv, float* __restrict__ out, int N)
{
    int wid = threadIdx.x >> 6, lane = threadIdx.x & 63;
    int n = blockIdx.x * 4 + wid;
    if (n >= N) return;
    int myhead = lane >> 4, myedge = lane & 15, grp = lane & 48;
    int lof = lane << 2;
    int off = offs[n], dg = deg[n];
    const int* cb = csr_src + off;
    float ar = aggr[(unsigned)(n * 4 + myhead)];

    float o0 = 0.f, o1 = 0.f, o2 = 0.f, o3 = 0.f;

    int cs0 = 0, cs1 = 0, cs2 = 0, cs3 = 0;
    int e1 = myedge + 16, e2 = myedge + 32, e3 = myedge + 48;
    if (myedge < dg) cs0 = cb[myedge];
    if (e1 < dg)     cs1 = cb[e1];
    if (e2 < dg)     cs2 = cb[e2];
    if (e3 < dg)     cs3 = cb[e3];
    float a0 = 0.f, a1 = 0.f, a2 = 0.f, a3 = 0.f;
    if (myedge < dg) a0 = aggl[(unsigned)((cs0 << 2) + myhead)];
    if (e1 < dg)     a1 = aggl[(unsigned)((cs1 << 2) + myhead)];
    if (e2 < dg)     a2 = aggl[(unsigned)((cs2 << 2) + myhead)];
    if (e3 < dg)     a3 = aggl[(unsigned)((cs3 << 2) + myhead)];
    float w0 = 0.f, w1 = 0.f, w2 = 0.f, w3 = 0.f;
    if (myedge < dg) { float e = a0 + ar; e = (e > 0.f) ? e : NEG_SLOPE * e; w0 = __expf(e); }
    if (e1 < dg)     { float e = a1 + ar; e = (e > 0.f) ? e : NEG_SLOPE * e; w1 = __expf(e); }
    if (e2 < dg)     { float e = a2 + ar; e = (e > 0.f) ? e : NEG_SLOPE * e; w2 = __expf(e); }
    if (e3 < dg)     { float e = a3 + ar; e = (e > 0.f) ? e : NEG_SLOPE * e; w3 = __expf(e); }
    float denom = w0; denom += w1; denom += w2; denom += w3;

    int c0 = dg < 16 ? dg : 16;
    do_chunk(cs0, w0, c0, grp, lof, xv, o0, o1, o2, o3);
    if (dg > 16) {
        int c1 = dg - 16 < 16 ? dg - 16 : 16;
        do_chunk(cs1, w1, c1, grp, lof, xv, o0, o1, o2, o3);
    }
    if (dg > 32) {
        int c2 = dg - 32 < 16 ? dg - 32 : 16;
        do_chunk(cs2, w2, c2, grp, lof, xv, o0, o1, o2, o3);
    }
    if (dg > 48) {
        int c3 = dg - 48 < 16 ? dg - 48 : 16;
        do_chunk(cs3, w3, c3, grp, lof, xv, o0, o1, o2, o3);
    }
    for (int b = 64; b < dg; b += 16) {
        int cs = 0; float w = 0.f;
        if (b + myedge < dg) {
            cs = cb[b + myedge];
            float e = aggl[(unsigned)((cs << 2) + myhead)] + ar;
            e = (e > 0.f) ? e : NEG_SLOPE * e;
            w = __expf(e);
        }
        denom += w;
        int cnt = dg - b < 16 ? dg - b : 16;
        do_chunk(cs, w, cnt, grp, lof, xv, o0, o1, o2, o3);
    }

#pragma unroll
    for (int o = 1; o <= 8; o <<= 1) denom += __shfl_xor(denom, o, 64);
    float inv = 1.0f / fmaxf(denom, 1e-16f);
    floatx4 res = {o0 * inv, o1 * inv, o2 * inv, o3 * inv};
    __builtin_nontemporal_store(res, (floatx4*)(out + (size_t)n * 256 + lof));
}

// ---------------------------------------------------------------------------
extern "C" void kernel_launch(void* const* d_in, const int* in_sizes, int n_in,
                              void* d_out, int out_size, void* d_ws, size_t ws_size,
                              hipStream_t stream)
{
    const float* x    = (const float*)d_in[0];
    const int*   src  = (const int*)d_in[1];
    const int*   dst  = (const int*)d_in[2];
    const float* Wl   = (const float*)d_in[3];
    const float* bl   = (const float*)d_in[4];
    const float* Wr   = (const float*)d_in[5];
    const float* br   = (const float*)d_in[6];
    const float* Wv   = (const float*)d_in[7];
    const float* bv   = (const float*)d_in[8];
    const float* attl = (const float*)d_in[9];
    const float* attr = (const float*)d_in[10];
    float* out = (float*)d_out;

    int N = in_sizes[0] / C_IN;
    int E = in_sizes[1];

    char* p = (char*)d_ws;
    auto alloc = [&](size_t bytes) -> void* {
        uintptr_t q = (uintptr_t)p;
        q = (q + 255) & ~(uintptr_t)255;
        p = (char*)(q + bytes);
        return (void*)q;
    };
    float* Ws     = (float*)alloc((size_t)C_IN * 8 * sizeof(float));
    float* bs     = (float*)alloc(8 * sizeof(float));
    float* s      = (float*)alloc((size_t)N * 8 * sizeof(float));
    float* aggl   = (float*)alloc((size_t)N * 4 * sizeof(float));
    float* aggr   = (float*)alloc((size_t)N * 4 * sizeof(float));
    int* deg      = (int*)alloc((size_t)N * sizeof(int));
    int* offs     = (int*)alloc((size_t)(N + 1) * sizeof(int));
    int* partials = (int*)alloc(256 * sizeof(int));
    int* csr_src  = (int*)alloc((size_t)E * sizeof(int));
    _Float16* WvT = (_Float16*)alloc((size_t)C_IN * C_OUT * sizeof(_Float16));
    _Float16* xv  = (_Float16*)alloc((size_t)N * C_OUT * sizeof(_Float16));

    // rank[i] lives in d_out: only attn_out writes out, AFTER scatter
    // consumed rank. E*4 = 3.2 MB << out_size = 51.2 MB.
    int* rank = (int*)d_out;

    hipMemsetAsync(deg, 0, (size_t)N * sizeof(int), stream);

    int deg_blocks = ((E + 3) / 4 + 255) / 256;
    prep_kernel<<<C_IN + 257 + deg_blocks, 256, 0, stream>>>(
        Wl, Wr, bl, br, attl, attr, Wv, dst, Ws, bs, WvT, deg, rank, E);
    gemm_xv<<<dim3((N + 63) / 64, C_OUT / 128), 256, 0, stream>>>(x, WvT, bv, Ws, bs, xv, s, N);
    int chunk = (N + 255) / 256;
    scan_part<<<256, 256, 0, stream>>>(deg, partials, N, chunk);
    scan_final<<<256, 256, 0, stream>>>(deg, partials, offs, N, chunk);
    scatter_kernel<<<((E + 3) / 4 + 255) / 256, 256, 0, stream>>>(src, dst, offs, rank, csr_src, E);
    agg_kernel<<<(N * 8 + 255) / 256, 256, 0, stream>>>(s, csr_src, offs, deg, aggl, aggr, N);
    attn_out<<<(N + 3) / 4, 256, 0, stream>>>(aggl, aggr, csr_src, offs, deg, xv, out, N);
}